// Round 8
// baseline (755.071 us; speedup 1.0000x reference)
//
#include <hip/hip_runtime.h>

// ---------------------------------------------------------------------------
// GCN forward: 3x (split-bf16 MFMA dual GEMM -> edge gather-agg -> BN-fused)
// -> CSR pooled readouts -> batched MLP head.
// Round 7: dispatch consolidation (33 -> 20 kernels): prep0 = deg+histm+wprep,
// merged dual scans (wave shfl top-scan), csr+mcsr, poolg+poolmg, stats via
// block partials + per-layer ticket last-block BN-finish; agg 8-deep unroll.
// ---------------------------------------------------------------------------

#define D128 128

typedef short bf16x8 __attribute__((ext_vector_type(8)));
typedef unsigned short u16x8 __attribute__((ext_vector_type(8)));
typedef float f32x4 __attribute__((ext_vector_type(4)));

static __device__ __forceinline__ unsigned short f2bf(float x) {
  unsigned u = __float_as_uint(x);
  unsigned r = (u + 0x7FFF + ((u >> 16) & 1)) >> 16;  // RNE
  return (unsigned short)r;
}
static __device__ __forceinline__ float bf2f(unsigned short b) {
  return __uint_as_float(((unsigned)b) << 16);
}

// prep0: [0,EB) edge degree hists; [EB,EB+NB) motif hist; [EB+NB,+48) wprep
__global__ __launch_bounds__(256) void k_prep0(
    const int* __restrict__ src, const int* __restrict__ dst,
    const int* __restrict__ mid, const float* __restrict__ Wg,
    const float* __restrict__ Wr, int* __restrict__ dego,
    int* __restrict__ degi, int* __restrict__ cntm,
    unsigned short* __restrict__ wp, int E, int N, int EB, int NB) {
  int b = blockIdx.x, t = threadIdx.x;
  if (b < EB) {
    int e = b * 256 + t;
    if (e < E) {
      atomicAdd(&dego[src[e]], 1);
      atomicAdd(&degi[dst[e]], 1);
    }
    return;
  }
  b -= EB;
  if (b < NB) {
    int i = b * 256 + t;
    if (i < N) atomicAdd(&cntm[mid[i]], 1);
    return;
  }
  b -= NB;
  int idx = b * 256 + t;  // < 12288
  int lane = idx & 63;
  int fs = (idx >> 6) & 31;
  int m = (idx >> 11) & 1;
  int l = idx >> 12;
  int cb = fs >> 2, s = fs & 3;
  const float* W = (m == 0 ? Wg : Wr) + (size_t)l * 16384;
  int n = cb * 16 + (lane & 15);
  int k0 = s * 32 + (lane >> 4) * 8;
  unsigned short* hi = wp + ((size_t)(l * 2 + m)) * 32768 + ((size_t)fs * 64 + lane) * 8;
  unsigned short* lo = hi + 16384;
#pragma unroll
  for (int j = 0; j < 8; ++j) {
    float x = W[(size_t)(k0 + j) * D128 + n];
    unsigned short h = f2bf(x);
    hi[j] = h;
    lo[j] = f2bf(x - bf2f(h));
  }
}

// norm + init scsh (scale=1, shift=0) for layer 0
__global__ void k_norm(const int* __restrict__ dego, const int* __restrict__ degi,
                       float* __restrict__ ns, float* __restrict__ nd,
                       float* __restrict__ scsh, int N) {
  int i = blockIdx.x * 256 + threadIdx.x;
  if (i < N) {
    ns[i] = rsqrtf(fmaxf((float)dego[i], 1.f));
    nd[i] = rsqrtf(fmaxf((float)degi[i], 1.f));
  }
  if (blockIdx.x == 0 && threadIdx.x < 128) {
    scsh[threadIdx.x] = 1.f;
    scsh[128 + threadIdx.x] = 0.f;
  }
}

// merged partial sums: blocks [0,nb1) over a1; blocks [nb1,..) over a2
__global__ __launch_bounds__(256) void k_part2(const int* __restrict__ a1,
                                               const int* __restrict__ a2,
                                               int* __restrict__ psum,
                                               int n1, int n2, int nb1) {
  int b = blockIdx.x, t = threadIdx.x;
  const int* a = a1;
  int n = n1, bb = b, out = b;
  if (b >= nb1) { a = a2; n = n2; bb = b - nb1; out = 64 + bb; }
  int i = bb * 1024 + t * 4;
  int4 v = make_int4(0, 0, 0, 0);
  if (i + 3 < n) v = *(const int4*)(a + i);
  else {
    if (i < n) v.x = a[i];
    if (i + 1 < n) v.y = a[i + 1];
    if (i + 2 < n) v.z = a[i + 2];
    if (i + 3 < n) v.w = a[i + 3];
  }
  int s = v.x + v.y + v.z + v.w;
#pragma unroll
  for (int off = 1; off < 64; off <<= 1) s += __shfl_xor(s, off);
  __shared__ int wsum[4];
  if ((t & 63) == 0) wsum[t >> 6] = s;
  __syncthreads();
  if (t == 0) psum[out] = wsum[0] + wsum[1] + wsum[2] + wsum[3];
}

// single block: two wave-level exclusive scans (nb1<=64, nb2<=64)
__global__ __launch_bounds__(128) void k_scanp2(int* __restrict__ psum, int nb1, int nb2) {
  int t = threadIdx.x;
  int lane = t & 63;
  int* p = (t < 64) ? psum : psum + 64;
  int nb = (t < 64) ? nb1 : nb2;
  int x = (lane < nb) ? p[lane] : 0;
  int s = x;
#pragma unroll
  for (int off = 1; off < 64; off <<= 1) {
    int u = __shfl_up(s, off);
    if (lane >= off) s += u;
  }
  if (lane < nb) p[lane] = s - x;
}

// merged scatter-scan
__global__ __launch_bounds__(256) void k_scat2(const int* __restrict__ a1,
                                               const int* __restrict__ a2,
                                               const int* __restrict__ psum,
                                               int* __restrict__ rp1,
                                               int* __restrict__ rp2,
                                               int n1, int n2, int nb1, int nb2) {
  int b = blockIdx.x, t = threadIdx.x;
  const int* a = a1;
  const int* ps = psum;
  int* rp = rp1;
  int n = n1, bb = b, nb = nb1;
  if (b >= nb1) { a = a2; ps = psum + 64; rp = rp2; n = n2; bb = b - nb1; nb = nb2; }
  int i = bb * 1024 + t * 4;
  int4 v = make_int4(0, 0, 0, 0);
  if (i + 3 < n) v = *(const int4*)(a + i);
  else {
    if (i < n) v.x = a[i];
    if (i + 1 < n) v.y = a[i + 1];
    if (i + 2 < n) v.z = a[i + 2];
    if (i + 3 < n) v.w = a[i + 3];
  }
  int s = v.x + v.y + v.z + v.w;
  __shared__ int buf[256];
  buf[t] = s;
  __syncthreads();
  for (int off = 1; off < 256; off <<= 1) {
    int u = (t >= off) ? buf[t - off] : 0;
    __syncthreads();
    buf[t] += u;
    __syncthreads();
  }
  int ex = buf[t] - s + ps[bb];
  int4 o;
  o.x = ex; o.y = ex + v.x; o.z = ex + v.x + v.y; o.w = ex + v.x + v.y + v.z;
  if (i + 3 < n) *(int4*)(rp + i) = o;
  else {
    if (i < n) rp[i] = o.x;
    if (i + 1 < n) rp[i + 1] = o.y;
    if (i + 2 < n) rp[i + 2] = o.z;
    if (i + 3 < n) rp[i + 3] = o.w;
  }
  if (bb == nb - 1 && t == 255) rp[n] = ex + s;
}

// merged CSR scatter: [0,EB) edges -> csrc ; [EB,EB+NB) nodes -> mlist
__global__ __launch_bounds__(256) void k_csrm(
    const int* __restrict__ src, const int* __restrict__ dst,
    const int* __restrict__ mid, const int* __restrict__ rp,
    const int* __restrict__ mrp, int* __restrict__ cur,
    int* __restrict__ mcur, int* __restrict__ csrc,
    int* __restrict__ mlist, int E, int N, int EB) {
  int b = blockIdx.x, t = threadIdx.x;
  if (b < EB) {
    int e = b * 256 + t;
    if (e < E) {
      int d = dst[e];
      int p = atomicAdd(&cur[d], 1);
      csrc[rp[d] + p] = src[e];
    }
    return;
  }
  int n = (b - EB) * 256 + t;
  if (n < N) {
    int m = mid[n];
    int p = atomicAdd(&mcur[m], 1);
    mlist[mrp[m] + p] = n;
  }
}

// split-bf16 MFMA dual GEMM: 64 rows x 256 cols (Wg|Wr) per block, 4 waves.
__global__ __launch_bounds__(256) void k_dualmfma(
    const float* __restrict__ h, const unsigned short* __restrict__ wpl,
    const float* __restrict__ brl, const float* __restrict__ ns,
    const float* __restrict__ scsh, unsigned short* __restrict__ hwb,
    float* __restrict__ res, int N) {
  __shared__ __align__(16) unsigned char smem[32768];  // hi[64][256B] | lo
  int t = threadIdx.x;
  int row0 = blockIdx.x * 64;
  const float* scale = scsh;
  const float* shift = scsh + 128;

#pragma unroll
  for (int q = 0; q < 4; ++q) {
    int chunk = q * 256 + t;
    int r = chunk >> 4;
    int c8 = chunk & 15;
    int gr = row0 + r;
    float xs[8];
    if (gr < N) {
      const float4* hp = (const float4*)(h + (size_t)gr * D128 + c8 * 8);
      float4 v0 = hp[0], v1 = hp[1];
      float4 sc0 = ((const float4*)scale)[c8 * 2];
      float4 sc1 = ((const float4*)scale)[c8 * 2 + 1];
      float4 sh0 = ((const float4*)shift)[c8 * 2];
      float4 sh1 = ((const float4*)shift)[c8 * 2 + 1];
      xs[0] = v0.x * sc0.x + sh0.x; xs[1] = v0.y * sc0.y + sh0.y;
      xs[2] = v0.z * sc0.z + sh0.z; xs[3] = v0.w * sc0.w + sh0.w;
      xs[4] = v1.x * sc1.x + sh1.x; xs[5] = v1.y * sc1.y + sh1.y;
      xs[6] = v1.z * sc1.z + sh1.z; xs[7] = v1.w * sc1.w + sh1.w;
    } else {
#pragma unroll
      for (int j = 0; j < 8; ++j) xs[j] = 0.f;
    }
    u16x8 hi8, lo8;
#pragma unroll
    for (int j = 0; j < 8; ++j) {
      unsigned short hb = f2bf(xs[j]);
      hi8[j] = hb;
      lo8[j] = f2bf(xs[j] - bf2f(hb));
    }
    int sw = (c8 * 16) ^ ((r & 7) << 4);
    *(u16x8*)(&smem[r * 256 + sw]) = hi8;
    *(u16x8*)(&smem[16384 + r * 256 + sw]) = lo8;
  }
  __syncthreads();

  int w = t >> 6, l6 = t & 63;
  int mat = w >> 1, half = w & 1;
  const unsigned short* wpm = wpl + (size_t)mat * 32768;

  f32x4 acc[4][4];
#pragma unroll
  for (int rb = 0; rb < 4; ++rb)
#pragma unroll
    for (int cb = 0; cb < 4; ++cb) acc[rb][cb] = (f32x4){0.f, 0.f, 0.f, 0.f};

#pragma unroll
  for (int s = 0; s < 4; ++s) {
    bf16x8 ah[4], al[4];
    int kb = s * 64 + (l6 >> 4) * 16;
#pragma unroll
    for (int rb = 0; rb < 4; ++rb) {
      int row = rb * 16 + (l6 & 15);
      int off = row * 256 + (kb ^ ((row & 7) << 4));
      ah[rb] = *(const bf16x8*)(&smem[off]);
      al[rb] = *(const bf16x8*)(&smem[16384 + off]);
    }
    bf16x8 bh[4], bl[4];
#pragma unroll
    for (int cb = 0; cb < 4; ++cb) {
      const unsigned short* p = wpm + (((size_t)(half * 4 + cb) * 4 + s) * 64 + l6) * 8;
      bh[cb] = *(const bf16x8*)p;
      bl[cb] = *(const bf16x8*)(p + 16384);
    }
#pragma unroll
    for (int rb = 0; rb < 4; ++rb)
#pragma unroll
      for (int cb = 0; cb < 4; ++cb) {
        acc[rb][cb] = __builtin_amdgcn_mfma_f32_16x16x32_bf16(ah[rb], bh[cb], acc[rb][cb], 0, 0, 0);
        acc[rb][cb] = __builtin_amdgcn_mfma_f32_16x16x32_bf16(al[rb], bh[cb], acc[rb][cb], 0, 0, 0);
        acc[rb][cb] = __builtin_amdgcn_mfma_f32_16x16x32_bf16(ah[rb], bl[cb], acc[rb][cb], 0, 0, 0);
      }
  }

  int rsub = (l6 >> 4) * 4;
  int colb = half * 64 + (l6 & 15);
  if (mat == 0) {
#pragma unroll
    for (int rb = 0; rb < 4; ++rb)
#pragma unroll
      for (int reg = 0; reg < 4; ++reg) {
        int gr = row0 + rb * 16 + rsub + reg;
        if (gr >= N) continue;
        float sv = ns[gr];
        unsigned short* op = hwb + ((size_t)gr << 7) + colb;
#pragma unroll
        for (int cb = 0; cb < 4; ++cb) op[cb * 16] = f2bf(acc[rb][cb][reg] * sv);
      }
  } else {
    float bv[4];
#pragma unroll
    for (int cb = 0; cb < 4; ++cb) bv[cb] = brl[colb + cb * 16];
#pragma unroll
    for (int rb = 0; rb < 4; ++rb)
#pragma unroll
      for (int reg = 0; reg < 4; ++reg) {
        int gr = row0 + rb * 16 + rsub + reg;
        if (gr >= N) continue;
        float* op = res + (size_t)gr * D128 + colb;
#pragma unroll
        for (int cb = 0; cb < 4; ++cb) op[cb * 16] = fmaxf(acc[rb][cb][reg] + bv[cb], 0.f);
      }
  }
}

// one wave per node: y = relu(agg*nd + bg) + res; 8-deep unrolled gathers
__global__ __launch_bounds__(256) void k_agg(
    const unsigned short* __restrict__ hwb, const int* __restrict__ rp,
    const int* __restrict__ csrc, const float* __restrict__ nd,
    const float* __restrict__ bgl, float* __restrict__ yres, int N) {
  int n = blockIdx.x * 4 + (threadIdx.x >> 6);
  int lane = threadIdx.x & 63;
  if (n >= N) return;
  int beg = rp[n], end = rp[n + 1];
  float ax = 0.f, ay = 0.f;
  for (int e0 = beg; e0 < end; e0 += 64) {
    int cnt = min(end - e0, 64);
    int sreg = (lane < cnt) ? csrc[e0 + lane] : 0;
    int j = 0;
    for (; j + 8 <= cnt; j += 8) {
      unsigned v[8];
#pragma unroll
      for (int u = 0; u < 8; ++u) {
        int s = __shfl(sreg, j + u);
        v[u] = *(const unsigned*)(hwb + (((size_t)s) << 7) + lane * 2);
      }
#pragma unroll
      for (int u = 0; u < 8; ++u) {
        ax += bf2f((unsigned short)(v[u] & 0xffffu));
        ay += bf2f((unsigned short)(v[u] >> 16));
      }
    }
    for (; j + 4 <= cnt; j += 4) {
      unsigned v[4];
#pragma unroll
      for (int u = 0; u < 4; ++u) {
        int s = __shfl(sreg, j + u);
        v[u] = *(const unsigned*)(hwb + (((size_t)s) << 7) + lane * 2);
      }
#pragma unroll
      for (int u = 0; u < 4; ++u) {
        ax += bf2f((unsigned short)(v[u] & 0xffffu));
        ay += bf2f((unsigned short)(v[u] >> 16));
      }
    }
    for (; j < cnt; ++j) {
      int s = __shfl(sreg, j);
      unsigned v = *(const unsigned*)(hwb + (((size_t)s) << 7) + lane * 2);
      ax += bf2f((unsigned short)(v & 0xffffu));
      ay += bf2f((unsigned short)(v >> 16));
    }
  }
  float ndv = nd[n];
  float2 b = ((const float2*)bgl)[lane];
  float2 r = ((const float2*)yres)[(size_t)n * 64 + lane];
  float2 y;
  y.x = fmaxf(ax * ndv + b.x, 0.f) + r.x;
  y.y = fmaxf(ay * ndv + b.y, 0.f) + r.y;
  ((float2*)yres)[(size_t)n * 64 + lane] = y;
}

// stats via block partials; ticket last-block computes BN scale/shift
__global__ __launch_bounds__(256) void k_statsfin(
    const float* __restrict__ y, float* __restrict__ parts,
    int* __restrict__ ticket, const float* __restrict__ gam,
    const float* __restrict__ bet, float* __restrict__ scsh,
    int N, float invN) {
  int t = threadIdx.x;
  int col = t & 127, half = t >> 7;
  float a = 0.f, q = 0.f;
  for (int r = blockIdx.x * 2 + half; r < N; r += gridDim.x * 2) {
    float v = y[(size_t)r * D128 + col];
    a += v; q += v * v;
  }
  __shared__ float ls[256], lq[256];
  ls[t] = a; lq[t] = q;
  __syncthreads();
  if (t < 128) {
    parts[(size_t)blockIdx.x * 256 + t] = ls[t] + ls[t + 128];
    parts[(size_t)blockIdx.x * 256 + 128 + t] = lq[t] + lq[t + 128];
  }
  __threadfence();
  __shared__ int tk;
  __syncthreads();
  if (t == 0) tk = atomicAdd(ticket, 1);
  __syncthreads();
  if (tk == (int)gridDim.x - 1) {
    __threadfence();
    if (t < 128) {
      float sum = 0.f, sq = 0.f;
      for (int b = 0; b < (int)gridDim.x; ++b) {
        sum += parts[(size_t)b * 256 + t];
        sq += parts[(size_t)b * 256 + 128 + t];
      }
      float mu = sum * invN;
      float var = sq * invN - mu * mu;
      float sc = gam[t] * rsqrtf(var + 1e-5f);
      scsh[t] = sc;
      scsh[128 + t] = bet[t] - mu * sc;
    }
  }
}

// merged pooling: blocks [0,G) graph pool; [G,G+M) motif pool via CSR
__global__ __launch_bounds__(256) void k_poolgm(
    const float* __restrict__ y, const int* __restrict__ gid,
    const int* __restrict__ mrp, const int* __restrict__ mlist,
    const float* __restrict__ scsh, float* __restrict__ out,
    float* __restrict__ xcat, int N, int G) {
  int b = blockIdx.x, t = threadIdx.x;
  int col = t & 127, half = t >> 7;
  const float* scale = scsh;
  const float* shift = scsh + 128;
  float acc = 0.f;
  int beg, end;
  if (b < G) {
    int g = b;
    int lo = 0, hi = N;
    while (lo < hi) { int m = (lo + hi) >> 1; if (gid[m] < g) lo = m + 1; else hi = m; }
    beg = lo;
    hi = N;
    while (lo < hi) { int m = (lo + hi) >> 1; if (gid[m] <= g) lo = m + 1; else hi = m; }
    end = lo;
    for (int r = beg + half; r < end; r += 2) acc += y[(size_t)r * D128 + col];
  } else {
    int m = b - G + 1;
    beg = mrp[m]; end = mrp[m + 1];
    for (int r = beg + half; r < end; r += 2) {
      int n = mlist[r];
      acc += y[(size_t)n * D128 + col];
    }
  }
  __shared__ float ls[256];
  ls[t] = acc;
  __syncthreads();
  if (t < 128) {
    float v = ls[t] + ls[t + 128];
    v = v / fmaxf((float)(end - beg), 1.f);
    v = v * scale[t] + shift[t];
    xcat[(size_t)b * D128 + t] = v;
    if (b < G) out[(size_t)b * D128 + t] = v;
  }
}

// tiled GEMM: out = act(X[M,K] @ W[K,N] + b), BM=64 BN=64 BK=32
__global__ __launch_bounds__(256) void k_gemm64(
    const float* __restrict__ X, const float* __restrict__ W,
    const float* __restrict__ b, float* __restrict__ out,
    int Mrows, int K, int Ncols, int relu) {
  __shared__ float xs[64][33];
  __shared__ float ws[32][68];
  int t = threadIdx.x;
  int row0 = blockIdx.x * 64, col0 = blockIdx.y * 64;
  int tx = t & 15, ty = t >> 4;
  int j0 = tx * 4, r0 = ty * 4;
  float acc[4][4] = {};
  for (int k0 = 0; k0 < K; k0 += 32) {
    for (int i = t; i < 512; i += 256) {
      int r = i >> 3, c4 = i & 7;
      int gr = row0 + r;
      float4 v = make_float4(0.f, 0.f, 0.f, 0.f);
      if (gr < Mrows) v = *(const float4*)(X + (size_t)gr * K + k0 + c4 * 4);
      xs[r][c4 * 4 + 0] = v.x; xs[r][c4 * 4 + 1] = v.y;
      xs[r][c4 * 4 + 2] = v.z; xs[r][c4 * 4 + 3] = v.w;
    }
    for (int i = t; i < 512; i += 256) {
      int r = i >> 4, c4 = i & 15;
      float4 v = *(const float4*)(W + (size_t)(k0 + r) * Ncols + col0 + c4 * 4);
      *(float4*)(&ws[r][c4 * 4]) = v;
    }
    __syncthreads();
#pragma unroll
    for (int kk = 0; kk < 32; ++kk) {
      float a_[4];
#pragma unroll
      for (int r = 0; r < 4; ++r) a_[r] = xs[r0 + r][kk];
      float4 wv = *(const float4*)(&ws[kk][j0]);
      float b_[4] = {wv.x, wv.y, wv.z, wv.w};
#pragma unroll
      for (int r = 0; r < 4; ++r)
#pragma unroll
        for (int j = 0; j < 4; ++j) acc[r][j] += a_[r] * b_[j];
    }
    __syncthreads();
  }
  float4 bb = *(const float4*)(b + col0 + j0);
  float ba[4] = {bb.x, bb.y, bb.z, bb.w};
#pragma unroll
  for (int r = 0; r < 4; ++r) {
    int gr = row0 + r0 + r;
    if (gr >= Mrows) continue;
    float4 o;
    o.x = acc[r][0] + ba[0]; o.y = acc[r][1] + ba[1];
    o.z = acc[r][2] + ba[2]; o.w = acc[r][3] + ba[3];
    if (relu) {
      o.x = fmaxf(o.x, 0.f); o.y = fmaxf(o.y, 0.f);
      o.z = fmaxf(o.z, 0.f); o.w = fmaxf(o.w, 0.f);
    }
    *(float4*)(out + (size_t)gr * Ncols + col0 + j0) = o;
  }
}

extern "C" void kernel_launch(void* const* d_in, const int* in_sizes, int n_in,
                              void* d_out, int out_size, void* d_ws, size_t ws_size,
                              hipStream_t stream) {
  (void)n_in; (void)out_size; (void)ws_size;
  const float* nf   = (const float*)d_in[0];
  const int*   src  = (const int*)d_in[1];
  const int*   dst  = (const int*)d_in[2];
  const int*   gid  = (const int*)d_in[3];
  const int*   mid  = (const int*)d_in[4];
  const float* Wg   = (const float*)d_in[5];
  const float* bg   = (const float*)d_in[6];
  const float* Wr   = (const float*)d_in[7];
  const float* br   = (const float*)d_in[8];
  const float* gam  = (const float*)d_in[9];
  const float* bet  = (const float*)d_in[10];
  const float* Wf   = (const float*)d_in[11];
  const float* bf   = (const float*)d_in[12];
  const float* W1   = (const float*)d_in[13];
  const float* b1   = (const float*)d_in[14];
  const float* W2   = (const float*)d_in[15];
  const float* b2   = (const float*)d_in[16];

  const int N = in_sizes[0] / D128;
  const int E = in_sizes[1];
  const int G = 512;
  const int M = 2048;
  const int R = G + M;

  char* ws = (char*)d_ws;
  size_t off = 0;
  auto alloc = [&](size_t bytes) -> void* {
    void* p = ws + off;
    off = (off + bytes + 255) & ~(size_t)255;
    return p;
  };
  unsigned short* hwb = (unsigned short*)alloc((size_t)N * D128 * 2);
  float* yres = (float*)alloc((size_t)N * D128 * 4);
  // zero block: dego | degi | cur | cntm | mcur | ticket[3]
  int*   zblk = (int*)alloc((size_t)(3 * N + 2 * (M + 1) + 3) * 4);
  int*   dego = zblk;
  int*   degi = zblk + N;
  int*   cur  = zblk + 2 * N;
  int*   cntm = zblk + 3 * N;
  int*   mcur = zblk + 3 * N + (M + 1);
  int*   ticket = zblk + 3 * N + 2 * (M + 1);
  float* ns   = (float*)alloc((size_t)N * 4);
  float* nd   = (float*)alloc((size_t)N * 4);
  int*   rp   = (int*)alloc((size_t)(N + 1) * 4);
  int*   mrp  = (int*)alloc((size_t)(M + 2) * 4);
  int*   csrc = (int*)alloc((size_t)E * 4);
  int*   mlist= (int*)alloc((size_t)N * 4);
  int*   psum = (int*)alloc(128 * 4);
  float* scsh = (float*)alloc(256 * 4);
  float* parts= (float*)alloc((size_t)256 * 256 * 4);
  unsigned short* wp = (unsigned short*)alloc((size_t)3 * 2 * 2 * 16384 * 2);
  float* xcat = (float*)alloc((size_t)R * D128 * 4);
  float* fbuf = (float*)alloc((size_t)R * 256 * 4);
  float* zbuf = (float*)alloc((size_t)R * 256 * 4);

  float* outg  = (float*)d_out;             // graph_feats [512,128]
  float* outgl = outg + (size_t)G * D128;   // out_global then out_sub

  const int EB = (E + 255) / 256;
  const int NB = (N + 255) / 256;
  const int nb1 = (N + 1023) / 1024;
  const int nb2 = (M + 1 + 1023) / 1024;

  hipMemsetAsync(zblk, 0, (size_t)(3 * N + 2 * (M + 1) + 3) * 4, stream);

  k_prep0<<<EB + NB + 48, 256, 0, stream>>>(src, dst, mid, Wg, Wr, dego, degi,
                                            cntm, wp, E, N, EB, NB);
  k_norm<<<NB, 256, 0, stream>>>(dego, degi, ns, nd, scsh, N);
  k_part2<<<nb1 + nb2, 256, 0, stream>>>(degi, cntm, psum, N, M + 1, nb1);
  k_scanp2<<<1, 128, 0, stream>>>(psum, nb1, nb2);
  k_scat2<<<nb1 + nb2, 256, 0, stream>>>(degi, cntm, psum, rp, mrp, N, M + 1, nb1, nb2);
  k_csrm<<<EB + NB, 256, 0, stream>>>(src, dst, mid, rp, mrp, cur, mcur,
                                      csrc, mlist, E, N, EB);

  const float* hin = nf;
  for (int l = 0; l < 3; ++l) {
    k_dualmfma<<<(N + 63) / 64, 256, 0, stream>>>(hin, wp + (size_t)l * 65536,
                                                  br + l * D128, ns, scsh, hwb, yres, N);
    k_agg<<<(N + 3) / 4, 256, 0, stream>>>(hwb, rp, csrc, nd, bg + l * D128, yres, N);
    k_statsfin<<<256, 256, 0, stream>>>(yres, parts, ticket + l, gam + l * D128,
                                        bet + l * D128, scsh, N, 1.f / (float)N);
    hin = yres;
  }

  k_poolgm<<<G + M, 256, 0, stream>>>(yres, gid, mrp, mlist, scsh, outg, xcat, N, G);

  dim3 g1((R + 63) / 64, 256 / 64);
  k_gemm64<<<g1, 256, 0, stream>>>(xcat, Wf, bf, fbuf, R, 128, 256, 0);
  dim3 g2((R + 63) / 64, 256 / 64);
  k_gemm64<<<g2, 256, 0, stream>>>(fbuf, W1, b1, zbuf, R, 256, 256, 1);
  dim3 g3((R + 63) / 64, 128 / 64);
  k_gemm64<<<g3, 256, 0, stream>>>(zbuf, W2, b2, outgl, R, 256, 128, 0);
}

// Round 9
// 633.460 us; speedup vs baseline: 1.1920x; 1.1920x over previous
//
#include <hip/hip_runtime.h>

// ---------------------------------------------------------------------------
// GCN forward: 3x (split-bf16 MFMA dual GEMM -> edge gather-agg -> BN-fused)
// -> CSR pooled readouts -> batched MLP head.
// Round 8: revert ticket-statsfin (serial last-block finish cost 108us) to
// atomics: vectorized k_stats (512 blk, float4, LDS tree) + k_bnfin that
// self-zeroes s12. Keep round-7 consolidations (prep0/scans/csrm/poolgm/agg8).
// ---------------------------------------------------------------------------

#define D128 128

typedef short bf16x8 __attribute__((ext_vector_type(8)));
typedef unsigned short u16x8 __attribute__((ext_vector_type(8)));
typedef float f32x4 __attribute__((ext_vector_type(4)));

static __device__ __forceinline__ unsigned short f2bf(float x) {
  unsigned u = __float_as_uint(x);
  unsigned r = (u + 0x7FFF + ((u >> 16) & 1)) >> 16;  // RNE
  return (unsigned short)r;
}
static __device__ __forceinline__ float bf2f(unsigned short b) {
  return __uint_as_float(((unsigned)b) << 16);
}

// prep0: [0,EB) edge degree hists; [EB,EB+NB) motif hist; [EB+NB,+48) wprep
__global__ __launch_bounds__(256) void k_prep0(
    const int* __restrict__ src, const int* __restrict__ dst,
    const int* __restrict__ mid, const float* __restrict__ Wg,
    const float* __restrict__ Wr, int* __restrict__ dego,
    int* __restrict__ degi, int* __restrict__ cntm,
    unsigned short* __restrict__ wp, int E, int N, int EB, int NB) {
  int b = blockIdx.x, t = threadIdx.x;
  if (b < EB) {
    int e = b * 256 + t;
    if (e < E) {
      atomicAdd(&dego[src[e]], 1);
      atomicAdd(&degi[dst[e]], 1);
    }
    return;
  }
  b -= EB;
  if (b < NB) {
    int i = b * 256 + t;
    if (i < N) atomicAdd(&cntm[mid[i]], 1);
    return;
  }
  b -= NB;
  int idx = b * 256 + t;  // < 12288
  int lane = idx & 63;
  int fs = (idx >> 6) & 31;
  int m = (idx >> 11) & 1;
  int l = idx >> 12;
  int cb = fs >> 2, s = fs & 3;
  const float* W = (m == 0 ? Wg : Wr) + (size_t)l * 16384;
  int n = cb * 16 + (lane & 15);
  int k0 = s * 32 + (lane >> 4) * 8;
  unsigned short* hi = wp + ((size_t)(l * 2 + m)) * 32768 + ((size_t)fs * 64 + lane) * 8;
  unsigned short* lo = hi + 16384;
#pragma unroll
  for (int j = 0; j < 8; ++j) {
    float x = W[(size_t)(k0 + j) * D128 + n];
    unsigned short h = f2bf(x);
    hi[j] = h;
    lo[j] = f2bf(x - bf2f(h));
  }
}

// norm + init scsh (scale=1, shift=0) for layer 0
__global__ void k_norm(const int* __restrict__ dego, const int* __restrict__ degi,
                       float* __restrict__ ns, float* __restrict__ nd,
                       float* __restrict__ scsh, int N) {
  int i = blockIdx.x * 256 + threadIdx.x;
  if (i < N) {
    ns[i] = rsqrtf(fmaxf((float)dego[i], 1.f));
    nd[i] = rsqrtf(fmaxf((float)degi[i], 1.f));
  }
  if (blockIdx.x == 0 && threadIdx.x < 128) {
    scsh[threadIdx.x] = 1.f;
    scsh[128 + threadIdx.x] = 0.f;
  }
}

// merged partial sums: blocks [0,nb1) over a1; blocks [nb1,..) over a2
__global__ __launch_bounds__(256) void k_part2(const int* __restrict__ a1,
                                               const int* __restrict__ a2,
                                               int* __restrict__ psum,
                                               int n1, int n2, int nb1) {
  int b = blockIdx.x, t = threadIdx.x;
  const int* a = a1;
  int n = n1, bb = b, out = b;
  if (b >= nb1) { a = a2; n = n2; bb = b - nb1; out = 64 + bb; }
  int i = bb * 1024 + t * 4;
  int4 v = make_int4(0, 0, 0, 0);
  if (i + 3 < n) v = *(const int4*)(a + i);
  else {
    if (i < n) v.x = a[i];
    if (i + 1 < n) v.y = a[i + 1];
    if (i + 2 < n) v.z = a[i + 2];
    if (i + 3 < n) v.w = a[i + 3];
  }
  int s = v.x + v.y + v.z + v.w;
#pragma unroll
  for (int off = 1; off < 64; off <<= 1) s += __shfl_xor(s, off);
  __shared__ int wsum[4];
  if ((t & 63) == 0) wsum[t >> 6] = s;
  __syncthreads();
  if (t == 0) psum[out] = wsum[0] + wsum[1] + wsum[2] + wsum[3];
}

// single block: two wave-level exclusive scans (nb1<=64, nb2<=64)
__global__ __launch_bounds__(128) void k_scanp2(int* __restrict__ psum, int nb1, int nb2) {
  int t = threadIdx.x;
  int lane = t & 63;
  int* p = (t < 64) ? psum : psum + 64;
  int nb = (t < 64) ? nb1 : nb2;
  int x = (lane < nb) ? p[lane] : 0;
  int s = x;
#pragma unroll
  for (int off = 1; off < 64; off <<= 1) {
    int u = __shfl_up(s, off);
    if (lane >= off) s += u;
  }
  if (lane < nb) p[lane] = s - x;
}

// merged scatter-scan
__global__ __launch_bounds__(256) void k_scat2(const int* __restrict__ a1,
                                               const int* __restrict__ a2,
                                               const int* __restrict__ psum,
                                               int* __restrict__ rp1,
                                               int* __restrict__ rp2,
                                               int n1, int n2, int nb1, int nb2) {
  int b = blockIdx.x, t = threadIdx.x;
  const int* a = a1;
  const int* ps = psum;
  int* rp = rp1;
  int n = n1, bb = b, nb = nb1;
  if (b >= nb1) { a = a2; ps = psum + 64; rp = rp2; n = n2; bb = b - nb1; nb = nb2; }
  int i = bb * 1024 + t * 4;
  int4 v = make_int4(0, 0, 0, 0);
  if (i + 3 < n) v = *(const int4*)(a + i);
  else {
    if (i < n) v.x = a[i];
    if (i + 1 < n) v.y = a[i + 1];
    if (i + 2 < n) v.z = a[i + 2];
    if (i + 3 < n) v.w = a[i + 3];
  }
  int s = v.x + v.y + v.z + v.w;
  __shared__ int buf[256];
  buf[t] = s;
  __syncthreads();
  for (int off = 1; off < 256; off <<= 1) {
    int u = (t >= off) ? buf[t - off] : 0;
    __syncthreads();
    buf[t] += u;
    __syncthreads();
  }
  int ex = buf[t] - s + ps[bb];
  int4 o;
  o.x = ex; o.y = ex + v.x; o.z = ex + v.x + v.y; o.w = ex + v.x + v.y + v.z;
  if (i + 3 < n) *(int4*)(rp + i) = o;
  else {
    if (i < n) rp[i] = o.x;
    if (i + 1 < n) rp[i + 1] = o.y;
    if (i + 2 < n) rp[i + 2] = o.z;
    if (i + 3 < n) rp[i + 3] = o.w;
  }
  if (bb == nb - 1 && t == 255) rp[n] = ex + s;
}

// merged CSR scatter: [0,EB) edges -> csrc ; [EB,EB+NB) nodes -> mlist
__global__ __launch_bounds__(256) void k_csrm(
    const int* __restrict__ src, const int* __restrict__ dst,
    const int* __restrict__ mid, const int* __restrict__ rp,
    const int* __restrict__ mrp, int* __restrict__ cur,
    int* __restrict__ mcur, int* __restrict__ csrc,
    int* __restrict__ mlist, int E, int N, int EB) {
  int b = blockIdx.x, t = threadIdx.x;
  if (b < EB) {
    int e = b * 256 + t;
    if (e < E) {
      int d = dst[e];
      int p = atomicAdd(&cur[d], 1);
      csrc[rp[d] + p] = src[e];
    }
    return;
  }
  int n = (b - EB) * 256 + t;
  if (n < N) {
    int m = mid[n];
    int p = atomicAdd(&mcur[m], 1);
    mlist[mrp[m] + p] = n;
  }
}

// split-bf16 MFMA dual GEMM: 64 rows x 256 cols (Wg|Wr) per block, 4 waves.
__global__ __launch_bounds__(256) void k_dualmfma(
    const float* __restrict__ h, const unsigned short* __restrict__ wpl,
    const float* __restrict__ brl, const float* __restrict__ ns,
    const float* __restrict__ scsh, unsigned short* __restrict__ hwb,
    float* __restrict__ res, int N) {
  __shared__ __align__(16) unsigned char smem[32768];  // hi[64][256B] | lo
  int t = threadIdx.x;
  int row0 = blockIdx.x * 64;
  const float* scale = scsh;
  const float* shift = scsh + 128;

#pragma unroll
  for (int q = 0; q < 4; ++q) {
    int chunk = q * 256 + t;
    int r = chunk >> 4;
    int c8 = chunk & 15;
    int gr = row0 + r;
    float xs[8];
    if (gr < N) {
      const float4* hp = (const float4*)(h + (size_t)gr * D128 + c8 * 8);
      float4 v0 = hp[0], v1 = hp[1];
      float4 sc0 = ((const float4*)scale)[c8 * 2];
      float4 sc1 = ((const float4*)scale)[c8 * 2 + 1];
      float4 sh0 = ((const float4*)shift)[c8 * 2];
      float4 sh1 = ((const float4*)shift)[c8 * 2 + 1];
      xs[0] = v0.x * sc0.x + sh0.x; xs[1] = v0.y * sc0.y + sh0.y;
      xs[2] = v0.z * sc0.z + sh0.z; xs[3] = v0.w * sc0.w + sh0.w;
      xs[4] = v1.x * sc1.x + sh1.x; xs[5] = v1.y * sc1.y + sh1.y;
      xs[6] = v1.z * sc1.z + sh1.z; xs[7] = v1.w * sc1.w + sh1.w;
    } else {
#pragma unroll
      for (int j = 0; j < 8; ++j) xs[j] = 0.f;
    }
    u16x8 hi8, lo8;
#pragma unroll
    for (int j = 0; j < 8; ++j) {
      unsigned short hb = f2bf(xs[j]);
      hi8[j] = hb;
      lo8[j] = f2bf(xs[j] - bf2f(hb));
    }
    int sw = (c8 * 16) ^ ((r & 7) << 4);
    *(u16x8*)(&smem[r * 256 + sw]) = hi8;
    *(u16x8*)(&smem[16384 + r * 256 + sw]) = lo8;
  }
  __syncthreads();

  int w = t >> 6, l6 = t & 63;
  int mat = w >> 1, half = w & 1;
  const unsigned short* wpm = wpl + (size_t)mat * 32768;

  f32x4 acc[4][4];
#pragma unroll
  for (int rb = 0; rb < 4; ++rb)
#pragma unroll
    for (int cb = 0; cb < 4; ++cb) acc[rb][cb] = (f32x4){0.f, 0.f, 0.f, 0.f};

#pragma unroll
  for (int s = 0; s < 4; ++s) {
    bf16x8 ah[4], al[4];
    int kb = s * 64 + (l6 >> 4) * 16;
#pragma unroll
    for (int rb = 0; rb < 4; ++rb) {
      int row = rb * 16 + (l6 & 15);
      int off = row * 256 + (kb ^ ((row & 7) << 4));
      ah[rb] = *(const bf16x8*)(&smem[off]);
      al[rb] = *(const bf16x8*)(&smem[16384 + off]);
    }
    bf16x8 bh[4], bl[4];
#pragma unroll
    for (int cb = 0; cb < 4; ++cb) {
      const unsigned short* p = wpm + (((size_t)(half * 4 + cb) * 4 + s) * 64 + l6) * 8;
      bh[cb] = *(const bf16x8*)p;
      bl[cb] = *(const bf16x8*)(p + 16384);
    }
#pragma unroll
    for (int rb = 0; rb < 4; ++rb)
#pragma unroll
      for (int cb = 0; cb < 4; ++cb) {
        acc[rb][cb] = __builtin_amdgcn_mfma_f32_16x16x32_bf16(ah[rb], bh[cb], acc[rb][cb], 0, 0, 0);
        acc[rb][cb] = __builtin_amdgcn_mfma_f32_16x16x32_bf16(al[rb], bh[cb], acc[rb][cb], 0, 0, 0);
        acc[rb][cb] = __builtin_amdgcn_mfma_f32_16x16x32_bf16(ah[rb], bl[cb], acc[rb][cb], 0, 0, 0);
      }
  }

  int rsub = (l6 >> 4) * 4;
  int colb = half * 64 + (l6 & 15);
  if (mat == 0) {
#pragma unroll
    for (int rb = 0; rb < 4; ++rb)
#pragma unroll
      for (int reg = 0; reg < 4; ++reg) {
        int gr = row0 + rb * 16 + rsub + reg;
        if (gr >= N) continue;
        float sv = ns[gr];
        unsigned short* op = hwb + ((size_t)gr << 7) + colb;
#pragma unroll
        for (int cb = 0; cb < 4; ++cb) op[cb * 16] = f2bf(acc[rb][cb][reg] * sv);
      }
  } else {
    float bv[4];
#pragma unroll
    for (int cb = 0; cb < 4; ++cb) bv[cb] = brl[colb + cb * 16];
#pragma unroll
    for (int rb = 0; rb < 4; ++rb)
#pragma unroll
      for (int reg = 0; reg < 4; ++reg) {
        int gr = row0 + rb * 16 + rsub + reg;
        if (gr >= N) continue;
        float* op = res + (size_t)gr * D128 + colb;
#pragma unroll
        for (int cb = 0; cb < 4; ++cb) op[cb * 16] = fmaxf(acc[rb][cb][reg] + bv[cb], 0.f);
      }
  }
}

// one wave per node: y = relu(agg*nd + bg) + res; 8-deep unrolled gathers
__global__ __launch_bounds__(256) void k_agg(
    const unsigned short* __restrict__ hwb, const int* __restrict__ rp,
    const int* __restrict__ csrc, const float* __restrict__ nd,
    const float* __restrict__ bgl, float* __restrict__ yres, int N) {
  int n = blockIdx.x * 4 + (threadIdx.x >> 6);
  int lane = threadIdx.x & 63;
  if (n >= N) return;
  int beg = rp[n], end = rp[n + 1];
  float ax = 0.f, ay = 0.f;
  for (int e0 = beg; e0 < end; e0 += 64) {
    int cnt = min(end - e0, 64);
    int sreg = (lane < cnt) ? csrc[e0 + lane] : 0;
    int j = 0;
    for (; j + 8 <= cnt; j += 8) {
      unsigned v[8];
#pragma unroll
      for (int u = 0; u < 8; ++u) {
        int s = __shfl(sreg, j + u);
        v[u] = *(const unsigned*)(hwb + (((size_t)s) << 7) + lane * 2);
      }
#pragma unroll
      for (int u = 0; u < 8; ++u) {
        ax += bf2f((unsigned short)(v[u] & 0xffffu));
        ay += bf2f((unsigned short)(v[u] >> 16));
      }
    }
    for (; j + 4 <= cnt; j += 4) {
      unsigned v[4];
#pragma unroll
      for (int u = 0; u < 4; ++u) {
        int s = __shfl(sreg, j + u);
        v[u] = *(const unsigned*)(hwb + (((size_t)s) << 7) + lane * 2);
      }
#pragma unroll
      for (int u = 0; u < 4; ++u) {
        ax += bf2f((unsigned short)(v[u] & 0xffffu));
        ay += bf2f((unsigned short)(v[u] >> 16));
      }
    }
    for (; j < cnt; ++j) {
      int s = __shfl(sreg, j);
      unsigned v = *(const unsigned*)(hwb + (((size_t)s) << 7) + lane * 2);
      ax += bf2f((unsigned short)(v & 0xffffu));
      ay += bf2f((unsigned short)(v >> 16));
    }
  }
  float ndv = nd[n];
  float2 b = ((const float2*)bgl)[lane];
  float2 r = ((const float2*)yres)[(size_t)n * 64 + lane];
  float2 y;
  y.x = fmaxf(ax * ndv + b.x, 0.f) + r.x;
  y.y = fmaxf(ay * ndv + b.y, 0.f) + r.y;
  ((float2*)yres)[(size_t)n * 64 + lane] = y;
}

// stats: float4 rows, 8 row-groups/block, LDS tree, atomicAdd into s12
__global__ __launch_bounds__(256) void k_stats(const float* __restrict__ y,
                                               float* __restrict__ s12, int N) {
  int t = threadIdx.x;
  int c4 = t & 31;         // float4 column index (cols c4*4..c4*4+3)
  int g = t >> 5;          // row group 0..7
  float4 a = make_float4(0.f, 0.f, 0.f, 0.f);
  float4 q = make_float4(0.f, 0.f, 0.f, 0.f);
  for (int r = blockIdx.x * 8 + g; r < N; r += gridDim.x * 8) {
    float4 v = ((const float4*)y)[(size_t)r * 32 + c4];
    a.x += v.x; a.y += v.y; a.z += v.z; a.w += v.w;
    q.x += v.x * v.x; q.y += v.y * v.y; q.z += v.z * v.z; q.w += v.w * v.w;
  }
  __shared__ float4 ls[256], lq[256];
  ls[t] = a; lq[t] = q;
  __syncthreads();
#pragma unroll
  for (int off = 128; off >= 32; off >>= 1) {
    if (t < off) {
      float4 u = ls[t + off], w = lq[t + off];
      ls[t].x += u.x; ls[t].y += u.y; ls[t].z += u.z; ls[t].w += u.w;
      lq[t].x += w.x; lq[t].y += w.y; lq[t].z += w.z; lq[t].w += w.w;
    }
    __syncthreads();
  }
  if (t < 32) {
    float4 u = ls[t], w = lq[t];
    atomicAdd(&s12[t * 4 + 0], u.x);
    atomicAdd(&s12[t * 4 + 1], u.y);
    atomicAdd(&s12[t * 4 + 2], u.z);
    atomicAdd(&s12[t * 4 + 3], u.w);
    atomicAdd(&s12[128 + t * 4 + 0], w.x);
    atomicAdd(&s12[128 + t * 4 + 1], w.y);
    atomicAdd(&s12[128 + t * 4 + 2], w.z);
    atomicAdd(&s12[128 + t * 4 + 3], w.w);
  }
}

// bnfin: compute scale/shift from s12, then re-zero s12 for the next layer
__global__ void k_bnfin(float* __restrict__ s12, const float* __restrict__ gam,
                        const float* __restrict__ bet, float* __restrict__ scsh,
                        float invN) {
  int j = threadIdx.x;
  float mu = s12[j] * invN;
  float var = s12[128 + j] * invN - mu * mu;
  float sc = gam[j] * rsqrtf(var + 1e-5f);
  scsh[j] = sc;
  scsh[128 + j] = bet[j] - mu * sc;
  s12[j] = 0.f;
  s12[128 + j] = 0.f;
}

// merged pooling: blocks [0,G) graph pool; [G,G+M) motif pool via CSR
__global__ __launch_bounds__(256) void k_poolgm(
    const float* __restrict__ y, const int* __restrict__ gid,
    const int* __restrict__ mrp, const int* __restrict__ mlist,
    const float* __restrict__ scsh, float* __restrict__ out,
    float* __restrict__ xcat, int N, int G) {
  int b = blockIdx.x, t = threadIdx.x;
  int col = t & 127, half = t >> 7;
  const float* scale = scsh;
  const float* shift = scsh + 128;
  float acc = 0.f;
  int beg, end;
  if (b < G) {
    int g = b;
    int lo = 0, hi = N;
    while (lo < hi) { int m = (lo + hi) >> 1; if (gid[m] < g) lo = m + 1; else hi = m; }
    beg = lo;
    hi = N;
    while (lo < hi) { int m = (lo + hi) >> 1; if (gid[m] <= g) lo = m + 1; else hi = m; }
    end = lo;
    for (int r = beg + half; r < end; r += 2) acc += y[(size_t)r * D128 + col];
  } else {
    int m = b - G + 1;
    beg = mrp[m]; end = mrp[m + 1];
    for (int r = beg + half; r < end; r += 2) {
      int n = mlist[r];
      acc += y[(size_t)n * D128 + col];
    }
  }
  __shared__ float ls[256];
  ls[t] = acc;
  __syncthreads();
  if (t < 128) {
    float v = ls[t] + ls[t + 128];
    v = v / fmaxf((float)(end - beg), 1.f);
    v = v * scale[t] + shift[t];
    xcat[(size_t)b * D128 + t] = v;
    if (b < G) out[(size_t)b * D128 + t] = v;
  }
}

// tiled GEMM: out = act(X[M,K] @ W[K,N] + b), BM=64 BN=64 BK=32
__global__ __launch_bounds__(256) void k_gemm64(
    const float* __restrict__ X, const float* __restrict__ W,
    const float* __restrict__ b, float* __restrict__ out,
    int Mrows, int K, int Ncols, int relu) {
  __shared__ float xs[64][33];
  __shared__ float ws[32][68];
  int t = threadIdx.x;
  int row0 = blockIdx.x * 64, col0 = blockIdx.y * 64;
  int tx = t & 15, ty = t >> 4;
  int j0 = tx * 4, r0 = ty * 4;
  float acc[4][4] = {};
  for (int k0 = 0; k0 < K; k0 += 32) {
    for (int i = t; i < 512; i += 256) {
      int r = i >> 3, c4 = i & 7;
      int gr = row0 + r;
      float4 v = make_float4(0.f, 0.f, 0.f, 0.f);
      if (gr < Mrows) v = *(const float4*)(X + (size_t)gr * K + k0 + c4 * 4);
      xs[r][c4 * 4 + 0] = v.x; xs[r][c4 * 4 + 1] = v.y;
      xs[r][c4 * 4 + 2] = v.z; xs[r][c4 * 4 + 3] = v.w;
    }
    for (int i = t; i < 512; i += 256) {
      int r = i >> 4, c4 = i & 15;
      float4 v = *(const float4*)(W + (size_t)(k0 + r) * Ncols + col0 + c4 * 4);
      *(float4*)(&ws[r][c4 * 4]) = v;
    }
    __syncthreads();
#pragma unroll
    for (int kk = 0; kk < 32; ++kk) {
      float a_[4];
#pragma unroll
      for (int r = 0; r < 4; ++r) a_[r] = xs[r0 + r][kk];
      float4 wv = *(const float4*)(&ws[kk][j0]);
      float b_[4] = {wv.x, wv.y, wv.z, wv.w};
#pragma unroll
      for (int r = 0; r < 4; ++r)
#pragma unroll
        for (int j = 0; j < 4; ++j) acc[r][j] += a_[r] * b_[j];
    }
    __syncthreads();
  }
  float4 bb = *(const float4*)(b + col0 + j0);
  float ba[4] = {bb.x, bb.y, bb.z, bb.w};
#pragma unroll
  for (int r = 0; r < 4; ++r) {
    int gr = row0 + r0 + r;
    if (gr >= Mrows) continue;
    float4 o;
    o.x = acc[r][0] + ba[0]; o.y = acc[r][1] + ba[1];
    o.z = acc[r][2] + ba[2]; o.w = acc[r][3] + ba[3];
    if (relu) {
      o.x = fmaxf(o.x, 0.f); o.y = fmaxf(o.y, 0.f);
      o.z = fmaxf(o.z, 0.f); o.w = fmaxf(o.w, 0.f);
    }
    *(float4*)(out + (size_t)gr * Ncols + col0 + j0) = o;
  }
}

extern "C" void kernel_launch(void* const* d_in, const int* in_sizes, int n_in,
                              void* d_out, int out_size, void* d_ws, size_t ws_size,
                              hipStream_t stream) {
  (void)n_in; (void)out_size; (void)ws_size;
  const float* nf   = (const float*)d_in[0];
  const int*   src  = (const int*)d_in[1];
  const int*   dst  = (const int*)d_in[2];
  const int*   gid  = (const int*)d_in[3];
  const int*   mid  = (const int*)d_in[4];
  const float* Wg   = (const float*)d_in[5];
  const float* bg   = (const float*)d_in[6];
  const float* Wr   = (const float*)d_in[7];
  const float* br   = (const float*)d_in[8];
  const float* gam  = (const float*)d_in[9];
  const float* bet  = (const float*)d_in[10];
  const float* Wf   = (const float*)d_in[11];
  const float* bf   = (const float*)d_in[12];
  const float* W1   = (const float*)d_in[13];
  const float* b1   = (const float*)d_in[14];
  const float* W2   = (const float*)d_in[15];
  const float* b2   = (const float*)d_in[16];

  const int N = in_sizes[0] / D128;
  const int E = in_sizes[1];
  const int G = 512;
  const int M = 2048;
  const int R = G + M;

  char* ws = (char*)d_ws;
  size_t off = 0;
  auto alloc = [&](size_t bytes) -> void* {
    void* p = ws + off;
    off = (off + bytes + 255) & ~(size_t)255;
    return p;
  };
  unsigned short* hwb = (unsigned short*)alloc((size_t)N * D128 * 2);
  float* yres = (float*)alloc((size_t)N * D128 * 4);
  // zero block: dego | degi | cur | cntm | mcur | s12[256]
  int*   zblk = (int*)alloc((size_t)(3 * N + 2 * (M + 1) + 256) * 4);
  int*   dego = zblk;
  int*   degi = zblk + N;
  int*   cur  = zblk + 2 * N;
  int*   cntm = zblk + 3 * N;
  int*   mcur = zblk + 3 * N + (M + 1);
  float* s12  = (float*)(zblk + 3 * N + 2 * (M + 1));
  float* ns   = (float*)alloc((size_t)N * 4);
  float* nd   = (float*)alloc((size_t)N * 4);
  int*   rp   = (int*)alloc((size_t)(N + 1) * 4);
  int*   mrp  = (int*)alloc((size_t)(M + 2) * 4);
  int*   csrc = (int*)alloc((size_t)E * 4);
  int*   mlist= (int*)alloc((size_t)N * 4);
  int*   psum = (int*)alloc(128 * 4);
  float* scsh = (float*)alloc(256 * 4);
  unsigned short* wp = (unsigned short*)alloc((size_t)3 * 2 * 2 * 16384 * 2);
  float* xcat = (float*)alloc((size_t)R * D128 * 4);
  float* fbuf = (float*)alloc((size_t)R * 256 * 4);
  float* zbuf = (float*)alloc((size_t)R * 256 * 4);

  float* outg  = (float*)d_out;             // graph_feats [512,128]
  float* outgl = outg + (size_t)G * D128;   // out_global then out_sub

  const int EB = (E + 255) / 256;
  const int NB = (N + 255) / 256;
  const int nb1 = (N + 1023) / 1024;
  const int nb2 = (M + 1 + 1023) / 1024;

  hipMemsetAsync(zblk, 0, (size_t)(3 * N + 2 * (M + 1) + 256) * 4, stream);

  k_prep0<<<EB + NB + 48, 256, 0, stream>>>(src, dst, mid, Wg, Wr, dego, degi,
                                            cntm, wp, E, N, EB, NB);
  k_norm<<<NB, 256, 0, stream>>>(dego, degi, ns, nd, scsh, N);
  k_part2<<<nb1 + nb2, 256, 0, stream>>>(degi, cntm, psum, N, M + 1, nb1);
  k_scanp2<<<1, 128, 0, stream>>>(psum, nb1, nb2);
  k_scat2<<<nb1 + nb2, 256, 0, stream>>>(degi, cntm, psum, rp, mrp, N, M + 1, nb1, nb2);
  k_csrm<<<EB + NB, 256, 0, stream>>>(src, dst, mid, rp, mrp, cur, mcur,
                                      csrc, mlist, E, N, EB);

  const float* hin = nf;
  for (int l = 0; l < 3; ++l) {
    k_dualmfma<<<(N + 63) / 64, 256, 0, stream>>>(hin, wp + (size_t)l * 65536,
                                                  br + l * D128, ns, scsh, hwb, yres, N);
    k_agg<<<(N + 3) / 4, 256, 0, stream>>>(hwb, rp, csrc, nd, bg + l * D128, yres, N);
    k_stats<<<512, 256, 0, stream>>>(yres, s12, N);
    k_bnfin<<<1, 128, 0, stream>>>(s12, gam + l * D128, bet + l * D128,
                                   scsh, 1.f / (float)N);
    hin = yres;
  }

  k_poolgm<<<G + M, 256, 0, stream>>>(yres, gid, mrp, mlist, scsh, outg, xcat, N, G);

  dim3 g1((R + 63) / 64, 256 / 64);
  k_gemm64<<<g1, 256, 0, stream>>>(xcat, Wf, bf, fbuf, R, 128, 256, 0);
  dim3 g2((R + 63) / 64, 256 / 64);
  k_gemm64<<<g2, 256, 0, stream>>>(fbuf, W1, b1, zbuf, R, 256, 256, 1);
  dim3 g3((R + 63) / 64, 128 / 64);
  k_gemm64<<<g3, 256, 0, stream>>>(zbuf, W2, b2, outgl, R, 256, 128, 0);
}

// Round 11
// 465.356 us; speedup vs baseline: 1.6226x; 1.3612x over previous
//
#include <hip/hip_runtime.h>

// ---------------------------------------------------------------------------
// GCN forward: 3x (split-bf16 MFMA dual GEMM -> fused gather-agg+BN-stats)
// -> CSR pooled readouts -> batched MLP head.
// Round 9/10: BN stats fused into k_agg (grid-stride, register accum, LDS
// cross-wave reduce, 32-banked atomics) -- deletes the 62us k_stats pass.
// (Round-10 resubmit: round-9 bench was a GPU-acquisition timeout, never ran.)
// ---------------------------------------------------------------------------

#define D128 128
#define SBANKS 32

typedef short bf16x8 __attribute__((ext_vector_type(8)));
typedef unsigned short u16x8 __attribute__((ext_vector_type(8)));
typedef float f32x4 __attribute__((ext_vector_type(4)));

static __device__ __forceinline__ unsigned short f2bf(float x) {
  unsigned u = __float_as_uint(x);
  unsigned r = (u + 0x7FFF + ((u >> 16) & 1)) >> 16;  // RNE
  return (unsigned short)r;
}
static __device__ __forceinline__ float bf2f(unsigned short b) {
  return __uint_as_float(((unsigned)b) << 16);
}

// prep0: [0,EB) edge degree hists; [EB,EB+NB) motif hist; [EB+NB,+48) wprep
__global__ __launch_bounds__(256) void k_prep0(
    const int* __restrict__ src, const int* __restrict__ dst,
    const int* __restrict__ mid, const float* __restrict__ Wg,
    const float* __restrict__ Wr, int* __restrict__ dego,
    int* __restrict__ degi, int* __restrict__ cntm,
    unsigned short* __restrict__ wp, int E, int N, int EB, int NB) {
  int b = blockIdx.x, t = threadIdx.x;
  if (b < EB) {
    int e = b * 256 + t;
    if (e < E) {
      atomicAdd(&dego[src[e]], 1);
      atomicAdd(&degi[dst[e]], 1);
    }
    return;
  }
  b -= EB;
  if (b < NB) {
    int i = b * 256 + t;
    if (i < N) atomicAdd(&cntm[mid[i]], 1);
    return;
  }
  b -= NB;
  int idx = b * 256 + t;  // < 12288
  int lane = idx & 63;
  int fs = (idx >> 6) & 31;
  int m = (idx >> 11) & 1;
  int l = idx >> 12;
  int cb = fs >> 2, s = fs & 3;
  const float* W = (m == 0 ? Wg : Wr) + (size_t)l * 16384;
  int n = cb * 16 + (lane & 15);
  int k0 = s * 32 + (lane >> 4) * 8;
  unsigned short* hi = wp + ((size_t)(l * 2 + m)) * 32768 + ((size_t)fs * 64 + lane) * 8;
  unsigned short* lo = hi + 16384;
#pragma unroll
  for (int j = 0; j < 8; ++j) {
    float x = W[(size_t)(k0 + j) * D128 + n];
    unsigned short h = f2bf(x);
    hi[j] = h;
    lo[j] = f2bf(x - bf2f(h));
  }
}

// norm + init scsh (scale=1, shift=0) for layer 0
__global__ void k_norm(const int* __restrict__ dego, const int* __restrict__ degi,
                       float* __restrict__ ns, float* __restrict__ nd,
                       float* __restrict__ scsh, int N) {
  int i = blockIdx.x * 256 + threadIdx.x;
  if (i < N) {
    ns[i] = rsqrtf(fmaxf((float)dego[i], 1.f));
    nd[i] = rsqrtf(fmaxf((float)degi[i], 1.f));
  }
  if (blockIdx.x == 0 && threadIdx.x < 128) {
    scsh[threadIdx.x] = 1.f;
    scsh[128 + threadIdx.x] = 0.f;
  }
}

// merged partial sums: blocks [0,nb1) over a1; blocks [nb1,..) over a2
__global__ __launch_bounds__(256) void k_part2(const int* __restrict__ a1,
                                               const int* __restrict__ a2,
                                               int* __restrict__ psum,
                                               int n1, int n2, int nb1) {
  int b = blockIdx.x, t = threadIdx.x;
  const int* a = a1;
  int n = n1, bb = b, out = b;
  if (b >= nb1) { a = a2; n = n2; bb = b - nb1; out = 64 + bb; }
  int i = bb * 1024 + t * 4;
  int4 v = make_int4(0, 0, 0, 0);
  if (i + 3 < n) v = *(const int4*)(a + i);
  else {
    if (i < n) v.x = a[i];
    if (i + 1 < n) v.y = a[i + 1];
    if (i + 2 < n) v.z = a[i + 2];
    if (i + 3 < n) v.w = a[i + 3];
  }
  int s = v.x + v.y + v.z + v.w;
#pragma unroll
  for (int off = 1; off < 64; off <<= 1) s += __shfl_xor(s, off);
  __shared__ int wsum[4];
  if ((t & 63) == 0) wsum[t >> 6] = s;
  __syncthreads();
  if (t == 0) psum[out] = wsum[0] + wsum[1] + wsum[2] + wsum[3];
}

// single block: two wave-level exclusive scans (nb1<=64, nb2<=64)
__global__ __launch_bounds__(128) void k_scanp2(int* __restrict__ psum, int nb1, int nb2) {
  int t = threadIdx.x;
  int lane = t & 63;
  int* p = (t < 64) ? psum : psum + 64;
  int nb = (t < 64) ? nb1 : nb2;
  int x = (lane < nb) ? p[lane] : 0;
  int s = x;
#pragma unroll
  for (int off = 1; off < 64; off <<= 1) {
    int u = __shfl_up(s, off);
    if (lane >= off) s += u;
  }
  if (lane < nb) p[lane] = s - x;
}

// merged scatter-scan
__global__ __launch_bounds__(256) void k_scat2(const int* __restrict__ a1,
                                               const int* __restrict__ a2,
                                               const int* __restrict__ psum,
                                               int* __restrict__ rp1,
                                               int* __restrict__ rp2,
                                               int n1, int n2, int nb1, int nb2) {
  int b = blockIdx.x, t = threadIdx.x;
  const int* a = a1;
  const int* ps = psum;
  int* rp = rp1;
  int n = n1, bb = b, nb = nb1;
  if (b >= nb1) { a = a2; ps = psum + 64; rp = rp2; n = n2; bb = b - nb1; nb = nb2; }
  int i = bb * 1024 + t * 4;
  int4 v = make_int4(0, 0, 0, 0);
  if (i + 3 < n) v = *(const int4*)(a + i);
  else {
    if (i < n) v.x = a[i];
    if (i + 1 < n) v.y = a[i + 1];
    if (i + 2 < n) v.z = a[i + 2];
    if (i + 3 < n) v.w = a[i + 3];
  }
  int s = v.x + v.y + v.z + v.w;
  __shared__ int buf[256];
  buf[t] = s;
  __syncthreads();
  for (int off = 1; off < 256; off <<= 1) {
    int u = (t >= off) ? buf[t - off] : 0;
    __syncthreads();
    buf[t] += u;
    __syncthreads();
  }
  int ex = buf[t] - s + ps[bb];
  int4 o;
  o.x = ex; o.y = ex + v.x; o.z = ex + v.x + v.y; o.w = ex + v.x + v.y + v.z;
  if (i + 3 < n) *(int4*)(rp + i) = o;
  else {
    if (i < n) rp[i] = o.x;
    if (i + 1 < n) rp[i + 1] = o.y;
    if (i + 2 < n) rp[i + 2] = o.z;
    if (i + 3 < n) rp[i + 3] = o.w;
  }
  if (bb == nb - 1 && t == 255) rp[n] = ex + s;
}

// merged CSR scatter: [0,EB) edges -> csrc ; [EB,EB+NB) nodes -> mlist
__global__ __launch_bounds__(256) void k_csrm(
    const int* __restrict__ src, const int* __restrict__ dst,
    const int* __restrict__ mid, const int* __restrict__ rp,
    const int* __restrict__ mrp, int* __restrict__ cur,
    int* __restrict__ mcur, int* __restrict__ csrc,
    int* __restrict__ mlist, int E, int N, int EB) {
  int b = blockIdx.x, t = threadIdx.x;
  if (b < EB) {
    int e = b * 256 + t;
    if (e < E) {
      int d = dst[e];
      int p = atomicAdd(&cur[d], 1);
      csrc[rp[d] + p] = src[e];
    }
    return;
  }
  int n = (b - EB) * 256 + t;
  if (n < N) {
    int m = mid[n];
    int p = atomicAdd(&mcur[m], 1);
    mlist[mrp[m] + p] = n;
  }
}

// split-bf16 MFMA dual GEMM: 64 rows x 256 cols (Wg|Wr) per block, 4 waves.
__global__ __launch_bounds__(256) void k_dualmfma(
    const float* __restrict__ h, const unsigned short* __restrict__ wpl,
    const float* __restrict__ brl, const float* __restrict__ ns,
    const float* __restrict__ scsh, unsigned short* __restrict__ hwb,
    float* __restrict__ res, int N) {
  __shared__ __align__(16) unsigned char smem[32768];  // hi[64][256B] | lo
  int t = threadIdx.x;
  int row0 = blockIdx.x * 64;
  const float* scale = scsh;
  const float* shift = scsh + 128;

#pragma unroll
  for (int q = 0; q < 4; ++q) {
    int chunk = q * 256 + t;
    int r = chunk >> 4;
    int c8 = chunk & 15;
    int gr = row0 + r;
    float xs[8];
    if (gr < N) {
      const float4* hp = (const float4*)(h + (size_t)gr * D128 + c8 * 8);
      float4 v0 = hp[0], v1 = hp[1];
      float4 sc0 = ((const float4*)scale)[c8 * 2];
      float4 sc1 = ((const float4*)scale)[c8 * 2 + 1];
      float4 sh0 = ((const float4*)shift)[c8 * 2];
      float4 sh1 = ((const float4*)shift)[c8 * 2 + 1];
      xs[0] = v0.x * sc0.x + sh0.x; xs[1] = v0.y * sc0.y + sh0.y;
      xs[2] = v0.z * sc0.z + sh0.z; xs[3] = v0.w * sc0.w + sh0.w;
      xs[4] = v1.x * sc1.x + sh1.x; xs[5] = v1.y * sc1.y + sh1.y;
      xs[6] = v1.z * sc1.z + sh1.z; xs[7] = v1.w * sc1.w + sh1.w;
    } else {
#pragma unroll
      for (int j = 0; j < 8; ++j) xs[j] = 0.f;
    }
    u16x8 hi8, lo8;
#pragma unroll
    for (int j = 0; j < 8; ++j) {
      unsigned short hb = f2bf(xs[j]);
      hi8[j] = hb;
      lo8[j] = f2bf(xs[j] - bf2f(hb));
    }
    int sw = (c8 * 16) ^ ((r & 7) << 4);
    *(u16x8*)(&smem[r * 256 + sw]) = hi8;
    *(u16x8*)(&smem[16384 + r * 256 + sw]) = lo8;
  }
  __syncthreads();

  int w = t >> 6, l6 = t & 63;
  int mat = w >> 1, half = w & 1;
  const unsigned short* wpm = wpl + (size_t)mat * 32768;

  f32x4 acc[4][4];
#pragma unroll
  for (int rb = 0; rb < 4; ++rb)
#pragma unroll
    for (int cb = 0; cb < 4; ++cb) acc[rb][cb] = (f32x4){0.f, 0.f, 0.f, 0.f};

#pragma unroll
  for (int s = 0; s < 4; ++s) {
    bf16x8 ah[4], al[4];
    int kb = s * 64 + (l6 >> 4) * 16;
#pragma unroll
    for (int rb = 0; rb < 4; ++rb) {
      int row = rb * 16 + (l6 & 15);
      int off = row * 256 + (kb ^ ((row & 7) << 4));
      ah[rb] = *(const bf16x8*)(&smem[off]);
      al[rb] = *(const bf16x8*)(&smem[16384 + off]);
    }
    bf16x8 bh[4], bl[4];
#pragma unroll
    for (int cb = 0; cb < 4; ++cb) {
      const unsigned short* p = wpm + (((size_t)(half * 4 + cb) * 4 + s) * 64 + l6) * 8;
      bh[cb] = *(const bf16x8*)p;
      bl[cb] = *(const bf16x8*)(p + 16384);
    }
#pragma unroll
    for (int rb = 0; rb < 4; ++rb)
#pragma unroll
      for (int cb = 0; cb < 4; ++cb) {
        acc[rb][cb] = __builtin_amdgcn_mfma_f32_16x16x32_bf16(ah[rb], bh[cb], acc[rb][cb], 0, 0, 0);
        acc[rb][cb] = __builtin_amdgcn_mfma_f32_16x16x32_bf16(al[rb], bh[cb], acc[rb][cb], 0, 0, 0);
        acc[rb][cb] = __builtin_amdgcn_mfma_f32_16x16x32_bf16(ah[rb], bl[cb], acc[rb][cb], 0, 0, 0);
      }
  }

  int rsub = (l6 >> 4) * 4;
  int colb = half * 64 + (l6 & 15);
  if (mat == 0) {
#pragma unroll
    for (int rb = 0; rb < 4; ++rb)
#pragma unroll
      for (int reg = 0; reg < 4; ++reg) {
        int gr = row0 + rb * 16 + rsub + reg;
        if (gr >= N) continue;
        float sv = ns[gr];
        unsigned short* op = hwb + ((size_t)gr << 7) + colb;
#pragma unroll
        for (int cb = 0; cb < 4; ++cb) op[cb * 16] = f2bf(acc[rb][cb][reg] * sv);
      }
  } else {
    float bv[4];
#pragma unroll
    for (int cb = 0; cb < 4; ++cb) bv[cb] = brl[colb + cb * 16];
#pragma unroll
    for (int rb = 0; rb < 4; ++rb)
#pragma unroll
      for (int reg = 0; reg < 4; ++reg) {
        int gr = row0 + rb * 16 + rsub + reg;
        if (gr >= N) continue;
        float* op = res + (size_t)gr * D128 + colb;
#pragma unroll
        for (int cb = 0; cb < 4; ++cb) op[cb * 16] = fmaxf(acc[rb][cb][reg] + bv[cb], 0.f);
      }
  }
}

// grid-stride agg + fused BN stats: y = relu(agg*nd+bg)+res -> yres;
// per-thread (sum,sumsq) for its 2 cols, LDS cross-wave reduce, banked atomics.
__global__ __launch_bounds__(256) void k_agg(
    const unsigned short* __restrict__ hwb, const int* __restrict__ rp,
    const int* __restrict__ csrc, const float* __restrict__ nd,
    const float* __restrict__ bgl, float* __restrict__ yres,
    float* __restrict__ s12b, int N) {
  int w = threadIdx.x >> 6, lane = threadIdx.x & 63;
  float2 b = ((const float2*)bgl)[lane];
  float sx = 0.f, sy = 0.f, qx = 0.f, qy = 0.f;
  for (int n = blockIdx.x * 4 + w; n < N; n += gridDim.x * 4) {
    int beg = rp[n], end = rp[n + 1];
    float ax = 0.f, ay = 0.f;
    for (int e0 = beg; e0 < end; e0 += 64) {
      int cnt = min(end - e0, 64);
      int sreg = (lane < cnt) ? csrc[e0 + lane] : 0;
      int j = 0;
      for (; j + 8 <= cnt; j += 8) {
        unsigned v[8];
#pragma unroll
        for (int u = 0; u < 8; ++u) {
          int s = __shfl(sreg, j + u);
          v[u] = *(const unsigned*)(hwb + (((size_t)s) << 7) + lane * 2);
        }
#pragma unroll
        for (int u = 0; u < 8; ++u) {
          ax += bf2f((unsigned short)(v[u] & 0xffffu));
          ay += bf2f((unsigned short)(v[u] >> 16));
        }
      }
      for (; j + 4 <= cnt; j += 4) {
        unsigned v[4];
#pragma unroll
        for (int u = 0; u < 4; ++u) {
          int s = __shfl(sreg, j + u);
          v[u] = *(const unsigned*)(hwb + (((size_t)s) << 7) + lane * 2);
        }
#pragma unroll
        for (int u = 0; u < 4; ++u) {
          ax += bf2f((unsigned short)(v[u] & 0xffffu));
          ay += bf2f((unsigned short)(v[u] >> 16));
        }
      }
      for (; j < cnt; ++j) {
        int s = __shfl(sreg, j);
        unsigned v = *(const unsigned*)(hwb + (((size_t)s) << 7) + lane * 2);
        ax += bf2f((unsigned short)(v & 0xffffu));
        ay += bf2f((unsigned short)(v >> 16));
      }
    }
    float ndv = nd[n];
    float2 r = ((const float2*)yres)[(size_t)n * 64 + lane];
    float2 y;
    y.x = fmaxf(ax * ndv + b.x, 0.f) + r.x;
    y.y = fmaxf(ay * ndv + b.y, 0.f) + r.y;
    ((float2*)yres)[(size_t)n * 64 + lane] = y;
    sx += y.x; sy += y.y;
    qx += y.x * y.x; qy += y.y * y.y;
  }
  // cross-wave reduce (4 waves) then banked atomics by wave 0
  __shared__ float2 ssum[4][64], ssq[4][64];
  ssum[w][lane] = make_float2(sx, sy);
  ssq[w][lane] = make_float2(qx, qy);
  __syncthreads();
  if (w == 0) {
    float2 a0 = ssum[0][lane], a1 = ssum[1][lane], a2 = ssum[2][lane], a3 = ssum[3][lane];
    float2 q0 = ssq[0][lane], q1 = ssq[1][lane], q2 = ssq[2][lane], q3 = ssq[3][lane];
    float ax = a0.x + a1.x + a2.x + a3.x;
    float ay = a0.y + a1.y + a2.y + a3.y;
    float qxx = q0.x + q1.x + q2.x + q3.x;
    float qyy = q0.y + q1.y + q2.y + q3.y;
    float* sb = s12b + (size_t)(blockIdx.x & (SBANKS - 1)) * 256;
    atomicAdd(&sb[lane * 2], ax);
    atomicAdd(&sb[lane * 2 + 1], ay);
    atomicAdd(&sb[128 + lane * 2], qxx);
    atomicAdd(&sb[128 + lane * 2 + 1], qyy);
  }
}

// bnfin: sum 32 banks, compute scale/shift, re-zero banks
__global__ void k_bnfin(float* __restrict__ s12b, const float* __restrict__ gam,
                        const float* __restrict__ bet, float* __restrict__ scsh,
                        float invN) {
  int j = threadIdx.x;  // 0..127 (column)
  float sum = 0.f, sq = 0.f;
#pragma unroll
  for (int bk = 0; bk < SBANKS; ++bk) {
    sum += s12b[(size_t)bk * 256 + j];
    sq += s12b[(size_t)bk * 256 + 128 + j];
  }
  float mu = sum * invN;
  float var = sq * invN - mu * mu;
  float sc = gam[j] * rsqrtf(var + 1e-5f);
  scsh[j] = sc;
  scsh[128 + j] = bet[j] - mu * sc;
#pragma unroll
  for (int bk = 0; bk < SBANKS; ++bk) {
    s12b[(size_t)bk * 256 + j] = 0.f;
    s12b[(size_t)bk * 256 + 128 + j] = 0.f;
  }
}

// merged pooling: blocks [0,G) graph pool; [G,G+M) motif pool via CSR
__global__ __launch_bounds__(256) void k_poolgm(
    const float* __restrict__ y, const int* __restrict__ gid,
    const int* __restrict__ mrp, const int* __restrict__ mlist,
    const float* __restrict__ scsh, float* __restrict__ out,
    float* __restrict__ xcat, int N, int G) {
  int b = blockIdx.x, t = threadIdx.x;
  int col = t & 127, half = t >> 7;
  const float* scale = scsh;
  const float* shift = scsh + 128;
  float acc = 0.f;
  int beg, end;
  if (b < G) {
    int g = b;
    int lo = 0, hi = N;
    while (lo < hi) { int m = (lo + hi) >> 1; if (gid[m] < g) lo = m + 1; else hi = m; }
    beg = lo;
    hi = N;
    while (lo < hi) { int m = (lo + hi) >> 1; if (gid[m] <= g) lo = m + 1; else hi = m; }
    end = lo;
    for (int r = beg + half; r < end; r += 2) acc += y[(size_t)r * D128 + col];
  } else {
    int m = b - G + 1;
    beg = mrp[m]; end = mrp[m + 1];
    for (int r = beg + half; r < end; r += 2) {
      int n = mlist[r];
      acc += y[(size_t)n * D128 + col];
    }
  }
  __shared__ float ls[256];
  ls[t] = acc;
  __syncthreads();
  if (t < 128) {
    float v = ls[t] + ls[t + 128];
    v = v / fmaxf((float)(end - beg), 1.f);
    v = v * scale[t] + shift[t];
    xcat[(size_t)b * D128 + t] = v;
    if (b < G) out[(size_t)b * D128 + t] = v;
  }
}

// tiled GEMM: out = act(X[M,K] @ W[K,N] + b), BM=64 BN=64 BK=32
__global__ __launch_bounds__(256) void k_gemm64(
    const float* __restrict__ X, const float* __restrict__ W,
    const float* __restrict__ b, float* __restrict__ out,
    int Mrows, int K, int Ncols, int relu) {
  __shared__ float xs[64][33];
  __shared__ float ws[32][68];
  int t = threadIdx.x;
  int row0 = blockIdx.x * 64, col0 = blockIdx.y * 64;
  int tx = t & 15, ty = t >> 4;
  int j0 = tx * 4, r0 = ty * 4;
  float acc[4][4] = {};
  for (int k0 = 0; k0 < K; k0 += 32) {
    for (int i = t; i < 512; i += 256) {
      int r = i >> 3, c4 = i & 7;
      int gr = row0 + r;
      float4 v = make_float4(0.f, 0.f, 0.f, 0.f);
      if (gr < Mrows) v = *(const float4*)(X + (size_t)gr * K + k0 + c4 * 4);
      xs[r][c4 * 4 + 0] = v.x; xs[r][c4 * 4 + 1] = v.y;
      xs[r][c4 * 4 + 2] = v.z; xs[r][c4 * 4 + 3] = v.w;
    }
    for (int i = t; i < 512; i += 256) {
      int r = i >> 4, c4 = i & 15;
      float4 v = *(const float4*)(W + (size_t)(k0 + r) * Ncols + col0 + c4 * 4);
      *(float4*)(&ws[r][c4 * 4]) = v;
    }
    __syncthreads();
#pragma unroll
    for (int kk = 0; kk < 32; ++kk) {
      float a_[4];
#pragma unroll
      for (int r = 0; r < 4; ++r) a_[r] = xs[r0 + r][kk];
      float4 wv = *(const float4*)(&ws[kk][j0]);
      float b_[4] = {wv.x, wv.y, wv.z, wv.w};
#pragma unroll
      for (int r = 0; r < 4; ++r)
#pragma unroll
        for (int j = 0; j < 4; ++j) acc[r][j] += a_[r] * b_[j];
    }
    __syncthreads();
  }
  float4 bb = *(const float4*)(b + col0 + j0);
  float ba[4] = {bb.x, bb.y, bb.z, bb.w};
#pragma unroll
  for (int r = 0; r < 4; ++r) {
    int gr = row0 + r0 + r;
    if (gr >= Mrows) continue;
    float4 o;
    o.x = acc[r][0] + ba[0]; o.y = acc[r][1] + ba[1];
    o.z = acc[r][2] + ba[2]; o.w = acc[r][3] + ba[3];
    if (relu) {
      o.x = fmaxf(o.x, 0.f); o.y = fmaxf(o.y, 0.f);
      o.z = fmaxf(o.z, 0.f); o.w = fmaxf(o.w, 0.f);
    }
    *(float4*)(out + (size_t)gr * Ncols + col0 + j0) = o;
  }
}

extern "C" void kernel_launch(void* const* d_in, const int* in_sizes, int n_in,
                              void* d_out, int out_size, void* d_ws, size_t ws_size,
                              hipStream_t stream) {
  (void)n_in; (void)out_size; (void)ws_size;
  const float* nf   = (const float*)d_in[0];
  const int*   src  = (const int*)d_in[1];
  const int*   dst  = (const int*)d_in[2];
  const int*   gid  = (const int*)d_in[3];
  const int*   mid  = (const int*)d_in[4];
  const float* Wg   = (const float*)d_in[5];
  const float* bg   = (const float*)d_in[6];
  const float* Wr   = (const float*)d_in[7];
  const float* br   = (const float*)d_in[8];
  const float* gam  = (const float*)d_in[9];
  const float* bet  = (const float*)d_in[10];
  const float* Wf   = (const float*)d_in[11];
  const float* bf   = (const float*)d_in[12];
  const float* W1   = (const float*)d_in[13];
  const float* b1   = (const float*)d_in[14];
  const float* W2   = (const float*)d_in[15];
  const float* b2   = (const float*)d_in[16];

  const int N = in_sizes[0] / D128;
  const int E = in_sizes[1];
  const int G = 512;
  const int M = 2048;
  const int R = G + M;

  char* ws = (char*)d_ws;
  size_t off = 0;
  auto alloc = [&](size_t bytes) -> void* {
    void* p = ws + off;
    off = (off + bytes + 255) & ~(size_t)255;
    return p;
  };
  unsigned short* hwb = (unsigned short*)alloc((size_t)N * D128 * 2);
  float* yres = (float*)alloc((size_t)N * D128 * 4);
  // zero block: dego | degi | cur | cntm | mcur | s12b[32*256]
  int*   zblk = (int*)alloc((size_t)(3 * N + 2 * (M + 1) + SBANKS * 256) * 4);
  int*   dego = zblk;
  int*   degi = zblk + N;
  int*   cur  = zblk + 2 * N;
  int*   cntm = zblk + 3 * N;
  int*   mcur = zblk + 3 * N + (M + 1);
  float* s12b = (float*)(zblk + 3 * N + 2 * (M + 1));
  float* ns   = (float*)alloc((size_t)N * 4);
  float* nd   = (float*)alloc((size_t)N * 4);
  int*   rp   = (int*)alloc((size_t)(N + 1) * 4);
  int*   mrp  = (int*)alloc((size_t)(M + 2) * 4);
  int*   csrc = (int*)alloc((size_t)E * 4);
  int*   mlist= (int*)alloc((size_t)N * 4);
  int*   psum = (int*)alloc(128 * 4);
  float* scsh = (float*)alloc(256 * 4);
  unsigned short* wp = (unsigned short*)alloc((size_t)3 * 2 * 2 * 16384 * 2);
  float* xcat = (float*)alloc((size_t)R * D128 * 4);
  float* fbuf = (float*)alloc((size_t)R * 256 * 4);
  float* zbuf = (float*)alloc((size_t)R * 256 * 4);

  float* outg  = (float*)d_out;             // graph_feats [512,128]
  float* outgl = outg + (size_t)G * D128;   // out_global then out_sub

  const int EB = (E + 255) / 256;
  const int NB = (N + 255) / 256;
  const int nb1 = (N + 1023) / 1024;
  const int nb2 = (M + 1 + 1023) / 1024;
  const int AGRID = 1024;

  hipMemsetAsync(zblk, 0, (size_t)(3 * N + 2 * (M + 1) + SBANKS * 256) * 4, stream);

  k_prep0<<<EB + NB + 48, 256, 0, stream>>>(src, dst, mid, Wg, Wr, dego, degi,
                                            cntm, wp, E, N, EB, NB);
  k_norm<<<NB, 256, 0, stream>>>(dego, degi, ns, nd, scsh, N);
  k_part2<<<nb1 + nb2, 256, 0, stream>>>(degi, cntm, psum, N, M + 1, nb1);
  k_scanp2<<<1, 128, 0, stream>>>(psum, nb1, nb2);
  k_scat2<<<nb1 + nb2, 256, 0, stream>>>(degi, cntm, psum, rp, mrp, N, M + 1, nb1, nb2);
  k_csrm<<<EB + NB, 256, 0, stream>>>(src, dst, mid, rp, mrp, cur, mcur,
                                      csrc, mlist, E, N, EB);

  const float* hin = nf;
  for (int l = 0; l < 3; ++l) {
    k_dualmfma<<<(N + 63) / 64, 256, 0, stream>>>(hin, wp + (size_t)l * 65536,
                                                  br + l * D128, ns, scsh, hwb, yres, N);
    k_agg<<<AGRID, 256, 0, stream>>>(hwb, rp, csrc, nd, bg + l * D128, yres, s12b, N);
    k_bnfin<<<1, 128, 0, stream>>>(s12b, gam + l * D128, bet + l * D128,
                                   scsh, 1.f / (float)N);
    hin = yres;
  }

  k_poolgm<<<G + M, 256, 0, stream>>>(yres, gid, mrp, mlist, scsh, outg, xcat, N, G);

  dim3 g1((R + 63) / 64, 256 / 64);
  k_gemm64<<<g1, 256, 0, stream>>>(xcat, Wf, bf, fbuf, R, 128, 256, 0);
  dim3 g2((R + 63) / 64, 256 / 64);
  k_gemm64<<<g2, 256, 0, stream>>>(fbuf, W1, b1, zbuf, R, 256, 256, 1);
  dim3 g3((R + 63) / 64, 128 / 64);
  k_gemm64<<<g3, 256, 0, stream>>>(zbuf, W2, b2, outgl, R, 256, 128, 0);
}

// Round 13
// 439.568 us; speedup vs baseline: 1.7178x; 1.0587x over previous
//
#include <hip/hip_runtime.h>

// ---------------------------------------------------------------------------
// GCN forward: 3x (split-bf16 MFMA dual GEMM -> fused gather-agg+BN-stats)
// -> CSR pooled readouts -> batched MLP head.
// Round 11/12: CSR scatter made atomic-free (prep0's histogram atomicAdd
// return value IS the per-edge ordinal -> stored pe/pn); res stored bf16;
// k_norm folded into k_part2.
// (Round-12 resubmit: round-11 bench was a GPU-acquisition timeout, never ran.)
// ---------------------------------------------------------------------------

#define D128 128
#define SBANKS 32

typedef short bf16x8 __attribute__((ext_vector_type(8)));
typedef unsigned short u16x8 __attribute__((ext_vector_type(8)));
typedef float f32x4 __attribute__((ext_vector_type(4)));

static __device__ __forceinline__ unsigned short f2bf(float x) {
  unsigned u = __float_as_uint(x);
  unsigned r = (u + 0x7FFF + ((u >> 16) & 1)) >> 16;  // RNE
  return (unsigned short)r;
}
static __device__ __forceinline__ float bf2f(unsigned short b) {
  return __uint_as_float(((unsigned)b) << 16);
}

// prep0: [0,EB) edge degree hists (stores pe); [EB,EB+NB) motif hist (stores
// pn); [EB+NB,+48) wprep
__global__ __launch_bounds__(256) void k_prep0(
    const int* __restrict__ src, const int* __restrict__ dst,
    const int* __restrict__ mid, const float* __restrict__ Wg,
    const float* __restrict__ Wr, int* __restrict__ dego,
    int* __restrict__ degi, int* __restrict__ cntm,
    int* __restrict__ pe, int* __restrict__ pn,
    unsigned short* __restrict__ wp, int E, int N, int EB, int NB) {
  int b = blockIdx.x, t = threadIdx.x;
  if (b < EB) {
    int e = b * 256 + t;
    if (e < E) {
      atomicAdd(&dego[src[e]], 1);
      pe[e] = atomicAdd(&degi[dst[e]], 1);
    }
    return;
  }
  b -= EB;
  if (b < NB) {
    int i = b * 256 + t;
    if (i < N) pn[i] = atomicAdd(&cntm[mid[i]], 1);
    return;
  }
  b -= NB;
  int idx = b * 256 + t;  // < 12288
  int lane = idx & 63;
  int fs = (idx >> 6) & 31;
  int m = (idx >> 11) & 1;
  int l = idx >> 12;
  int cb = fs >> 2, s = fs & 3;
  const float* W = (m == 0 ? Wg : Wr) + (size_t)l * 16384;
  int n = cb * 16 + (lane & 15);
  int k0 = s * 32 + (lane >> 4) * 8;
  unsigned short* hi = wp + ((size_t)(l * 2 + m)) * 32768 + ((size_t)fs * 64 + lane) * 8;
  unsigned short* lo = hi + 16384;
#pragma unroll
  for (int j = 0; j < 8; ++j) {
    float x = W[(size_t)(k0 + j) * D128 + n];
    unsigned short h = f2bf(x);
    hi[j] = h;
    lo[j] = f2bf(x - bf2f(h));
  }
}

// part2 (+norm): blocks [0,NB): norm + scsh init; [NB,NB+nb1): partials over
// degi; [NB+nb1,..): partials over cntm
__global__ __launch_bounds__(256) void k_part2(
    const int* __restrict__ dego, const int* __restrict__ degi,
    const int* __restrict__ cntm, float* __restrict__ ns,
    float* __restrict__ nd, float* __restrict__ scsh,
    int* __restrict__ psum, int N, int M1, int NB, int nb1) {
  int b = blockIdx.x, t = threadIdx.x;
  if (b < NB) {
    int i = b * 256 + t;
    if (i < N) {
      ns[i] = rsqrtf(fmaxf((float)dego[i], 1.f));
      nd[i] = rsqrtf(fmaxf((float)degi[i], 1.f));
    }
    if (b == 0 && t < 128) {
      scsh[t] = 1.f;
      scsh[128 + t] = 0.f;
    }
    return;
  }
  b -= NB;
  const int* a = degi;
  int n = N, bb = b, out = b;
  if (b >= nb1) { a = cntm; n = M1; bb = b - nb1; out = 64 + bb; }
  int i = bb * 1024 + t * 4;
  int4 v = make_int4(0, 0, 0, 0);
  if (i + 3 < n) v = *(const int4*)(a + i);
  else {
    if (i < n) v.x = a[i];
    if (i + 1 < n) v.y = a[i + 1];
    if (i + 2 < n) v.z = a[i + 2];
    if (i + 3 < n) v.w = a[i + 3];
  }
  int s = v.x + v.y + v.z + v.w;
#pragma unroll
  for (int off = 1; off < 64; off <<= 1) s += __shfl_xor(s, off);
  __shared__ int wsum[4];
  if ((t & 63) == 0) wsum[t >> 6] = s;
  __syncthreads();
  if (t == 0) psum[out] = wsum[0] + wsum[1] + wsum[2] + wsum[3];
}

// single block: two wave-level exclusive scans (nb1<=64, nb2<=64)
__global__ __launch_bounds__(128) void k_scanp2(int* __restrict__ psum, int nb1, int nb2) {
  int t = threadIdx.x;
  int lane = t & 63;
  int* p = (t < 64) ? psum : psum + 64;
  int nb = (t < 64) ? nb1 : nb2;
  int x = (lane < nb) ? p[lane] : 0;
  int s = x;
#pragma unroll
  for (int off = 1; off < 64; off <<= 1) {
    int u = __shfl_up(s, off);
    if (lane >= off) s += u;
  }
  if (lane < nb) p[lane] = s - x;
}

// merged scatter-scan
__global__ __launch_bounds__(256) void k_scat2(const int* __restrict__ a1,
                                               const int* __restrict__ a2,
                                               const int* __restrict__ psum,
                                               int* __restrict__ rp1,
                                               int* __restrict__ rp2,
                                               int n1, int n2, int nb1, int nb2) {
  int b = blockIdx.x, t = threadIdx.x;
  const int* a = a1;
  const int* ps = psum;
  int* rp = rp1;
  int n = n1, bb = b, nb = nb1;
  if (b >= nb1) { a = a2; ps = psum + 64; rp = rp2; n = n2; bb = b - nb1; nb = nb2; }
  int i = bb * 1024 + t * 4;
  int4 v = make_int4(0, 0, 0, 0);
  if (i + 3 < n) v = *(const int4*)(a + i);
  else {
    if (i < n) v.x = a[i];
    if (i + 1 < n) v.y = a[i + 1];
    if (i + 2 < n) v.z = a[i + 2];
    if (i + 3 < n) v.w = a[i + 3];
  }
  int s = v.x + v.y + v.z + v.w;
  __shared__ int buf[256];
  buf[t] = s;
  __syncthreads();
  for (int off = 1; off < 256; off <<= 1) {
    int u = (t >= off) ? buf[t - off] : 0;
    __syncthreads();
    buf[t] += u;
    __syncthreads();
  }
  int ex = buf[t] - s + ps[bb];
  int4 o;
  o.x = ex; o.y = ex + v.x; o.z = ex + v.x + v.y; o.w = ex + v.x + v.y + v.z;
  if (i + 3 < n) *(int4*)(rp + i) = o;
  else {
    if (i < n) rp[i] = o.x;
    if (i + 1 < n) rp[i + 1] = o.y;
    if (i + 2 < n) rp[i + 2] = o.z;
    if (i + 3 < n) rp[i + 3] = o.w;
  }
  if (bb == nb - 1 && t == 255) rp[n] = ex + s;
}

// ATOMIC-FREE CSR scatter using stored ordinals pe/pn:
// [0,EB) edges -> csrc ; [EB,EB+NB) nodes -> mlist
__global__ __launch_bounds__(256) void k_csrm(
    const int* __restrict__ src, const int* __restrict__ dst,
    const int* __restrict__ pe, const int* __restrict__ mid,
    const int* __restrict__ pn, const int* __restrict__ rp,
    const int* __restrict__ mrp, int* __restrict__ csrc,
    int* __restrict__ mlist, int E, int N, int EB) {
  int b = blockIdx.x, t = threadIdx.x;
  if (b < EB) {
    int e = b * 256 + t;
    if (e < E) {
      int d = dst[e];
      csrc[rp[d] + pe[e]] = src[e];
    }
    return;
  }
  int n = (b - EB) * 256 + t;
  if (n < N) {
    int m = mid[n];
    mlist[mrp[m] + pn[n]] = n;
  }
}

// split-bf16 MFMA dual GEMM: 64 rows x 256 cols (Wg|Wr) per block, 4 waves.
// hwb (bf16) = (hn @ Wg) * ns ; resb (bf16) = relu(hn @ Wr + br)
__global__ __launch_bounds__(256) void k_dualmfma(
    const float* __restrict__ h, const unsigned short* __restrict__ wpl,
    const float* __restrict__ brl, const float* __restrict__ ns,
    const float* __restrict__ scsh, unsigned short* __restrict__ hwb,
    unsigned short* __restrict__ resb, int N) {
  __shared__ __align__(16) unsigned char smem[32768];  // hi[64][256B] | lo
  int t = threadIdx.x;
  int row0 = blockIdx.x * 64;
  const float* scale = scsh;
  const float* shift = scsh + 128;

#pragma unroll
  for (int q = 0; q < 4; ++q) {
    int chunk = q * 256 + t;
    int r = chunk >> 4;
    int c8 = chunk & 15;
    int gr = row0 + r;
    float xs[8];
    if (gr < N) {
      const float4* hp = (const float4*)(h + (size_t)gr * D128 + c8 * 8);
      float4 v0 = hp[0], v1 = hp[1];
      float4 sc0 = ((const float4*)scale)[c8 * 2];
      float4 sc1 = ((const float4*)scale)[c8 * 2 + 1];
      float4 sh0 = ((const float4*)shift)[c8 * 2];
      float4 sh1 = ((const float4*)shift)[c8 * 2 + 1];
      xs[0] = v0.x * sc0.x + sh0.x; xs[1] = v0.y * sc0.y + sh0.y;
      xs[2] = v0.z * sc0.z + sh0.z; xs[3] = v0.w * sc0.w + sh0.w;
      xs[4] = v1.x * sc1.x + sh1.x; xs[5] = v1.y * sc1.y + sh1.y;
      xs[6] = v1.z * sc1.z + sh1.z; xs[7] = v1.w * sc1.w + sh1.w;
    } else {
#pragma unroll
      for (int j = 0; j < 8; ++j) xs[j] = 0.f;
    }
    u16x8 hi8, lo8;
#pragma unroll
    for (int j = 0; j < 8; ++j) {
      unsigned short hb = f2bf(xs[j]);
      hi8[j] = hb;
      lo8[j] = f2bf(xs[j] - bf2f(hb));
    }
    int sw = (c8 * 16) ^ ((r & 7) << 4);
    *(u16x8*)(&smem[r * 256 + sw]) = hi8;
    *(u16x8*)(&smem[16384 + r * 256 + sw]) = lo8;
  }
  __syncthreads();

  int w = t >> 6, l6 = t & 63;
  int mat = w >> 1, half = w & 1;
  const unsigned short* wpm = wpl + (size_t)mat * 32768;

  f32x4 acc[4][4];
#pragma unroll
  for (int rb = 0; rb < 4; ++rb)
#pragma unroll
    for (int cb = 0; cb < 4; ++cb) acc[rb][cb] = (f32x4){0.f, 0.f, 0.f, 0.f};

#pragma unroll
  for (int s = 0; s < 4; ++s) {
    bf16x8 ah[4], al[4];
    int kb = s * 64 + (l6 >> 4) * 16;
#pragma unroll
    for (int rb = 0; rb < 4; ++rb) {
      int row = rb * 16 + (l6 & 15);
      int off = row * 256 + (kb ^ ((row & 7) << 4));
      ah[rb] = *(const bf16x8*)(&smem[off]);
      al[rb] = *(const bf16x8*)(&smem[16384 + off]);
    }
    bf16x8 bh[4], bl[4];
#pragma unroll
    for (int cb = 0; cb < 4; ++cb) {
      const unsigned short* p = wpm + (((size_t)(half * 4 + cb) * 4 + s) * 64 + l6) * 8;
      bh[cb] = *(const bf16x8*)p;
      bl[cb] = *(const bf16x8*)(p + 16384);
    }
#pragma unroll
    for (int rb = 0; rb < 4; ++rb)
#pragma unroll
      for (int cb = 0; cb < 4; ++cb) {
        acc[rb][cb] = __builtin_amdgcn_mfma_f32_16x16x32_bf16(ah[rb], bh[cb], acc[rb][cb], 0, 0, 0);
        acc[rb][cb] = __builtin_amdgcn_mfma_f32_16x16x32_bf16(al[rb], bh[cb], acc[rb][cb], 0, 0, 0);
        acc[rb][cb] = __builtin_amdgcn_mfma_f32_16x16x32_bf16(ah[rb], bl[cb], acc[rb][cb], 0, 0, 0);
      }
  }

  int rsub = (l6 >> 4) * 4;
  int colb = half * 64 + (l6 & 15);
  if (mat == 0) {
#pragma unroll
    for (int rb = 0; rb < 4; ++rb)
#pragma unroll
      for (int reg = 0; reg < 4; ++reg) {
        int gr = row0 + rb * 16 + rsub + reg;
        if (gr >= N) continue;
        float sv = ns[gr];
        unsigned short* op = hwb + ((size_t)gr << 7) + colb;
#pragma unroll
        for (int cb = 0; cb < 4; ++cb) op[cb * 16] = f2bf(acc[rb][cb][reg] * sv);
      }
  } else {
    float bv[4];
#pragma unroll
    for (int cb = 0; cb < 4; ++cb) bv[cb] = brl[colb + cb * 16];
#pragma unroll
    for (int rb = 0; rb < 4; ++rb)
#pragma unroll
      for (int reg = 0; reg < 4; ++reg) {
        int gr = row0 + rb * 16 + rsub + reg;
        if (gr >= N) continue;
        unsigned short* op = resb + ((size_t)gr << 7) + colb;
#pragma unroll
        for (int cb = 0; cb < 4; ++cb)
          op[cb * 16] = f2bf(fmaxf(acc[rb][cb][reg] + bv[cb], 0.f));
      }
  }
}

// grid-stride agg + fused BN stats: y = relu(agg*nd+bg)+res(bf16) -> yres f32;
// per-thread (sum,sumsq), LDS cross-wave reduce, banked atomics.
__global__ __launch_bounds__(256) void k_agg(
    const unsigned short* __restrict__ hwb, const unsigned short* __restrict__ resb,
    const int* __restrict__ rp, const int* __restrict__ csrc,
    const float* __restrict__ nd, const float* __restrict__ bgl,
    float* __restrict__ yres, float* __restrict__ s12b, int N) {
  int w = threadIdx.x >> 6, lane = threadIdx.x & 63;
  float2 b = ((const float2*)bgl)[lane];
  float sx = 0.f, sy = 0.f, qx = 0.f, qy = 0.f;
  for (int n = blockIdx.x * 4 + w; n < N; n += gridDim.x * 4) {
    int beg = rp[n], end = rp[n + 1];
    float ax = 0.f, ay = 0.f;
    for (int e0 = beg; e0 < end; e0 += 64) {
      int cnt = min(end - e0, 64);
      int sreg = (lane < cnt) ? csrc[e0 + lane] : 0;
      int j = 0;
      for (; j + 8 <= cnt; j += 8) {
        unsigned v[8];
#pragma unroll
        for (int u = 0; u < 8; ++u) {
          int s = __shfl(sreg, j + u);
          v[u] = *(const unsigned*)(hwb + (((size_t)s) << 7) + lane * 2);
        }
#pragma unroll
        for (int u = 0; u < 8; ++u) {
          ax += bf2f((unsigned short)(v[u] & 0xffffu));
          ay += bf2f((unsigned short)(v[u] >> 16));
        }
      }
      for (; j + 4 <= cnt; j += 4) {
        unsigned v[4];
#pragma unroll
        for (int u = 0; u < 4; ++u) {
          int s = __shfl(sreg, j + u);
          v[u] = *(const unsigned*)(hwb + (((size_t)s) << 7) + lane * 2);
        }
#pragma unroll
        for (int u = 0; u < 4; ++u) {
          ax += bf2f((unsigned short)(v[u] & 0xffffu));
          ay += bf2f((unsigned short)(v[u] >> 16));
        }
      }
      for (; j < cnt; ++j) {
        int s = __shfl(sreg, j);
        unsigned v = *(const unsigned*)(hwb + (((size_t)s) << 7) + lane * 2);
        ax += bf2f((unsigned short)(v & 0xffffu));
        ay += bf2f((unsigned short)(v >> 16));
      }
    }
    float ndv = nd[n];
    unsigned rv = *(const unsigned*)(resb + (((size_t)n) << 7) + lane * 2);
    float2 y;
    y.x = fmaxf(ax * ndv + b.x, 0.f) + bf2f((unsigned short)(rv & 0xffffu));
    y.y = fmaxf(ay * ndv + b.y, 0.f) + bf2f((unsigned short)(rv >> 16));
    ((float2*)yres)[(size_t)n * 64 + lane] = y;
    sx += y.x; sy += y.y;
    qx += y.x * y.x; qy += y.y * y.y;
  }
  __shared__ float2 ssum[4][64], ssq[4][64];
  ssum[w][lane] = make_float2(sx, sy);
  ssq[w][lane] = make_float2(qx, qy);
  __syncthreads();
  if (w == 0) {
    float2 a0 = ssum[0][lane], a1 = ssum[1][lane], a2 = ssum[2][lane], a3 = ssum[3][lane];
    float2 q0 = ssq[0][lane], q1 = ssq[1][lane], q2 = ssq[2][lane], q3 = ssq[3][lane];
    float ax = a0.x + a1.x + a2.x + a3.x;
    float ay = a0.y + a1.y + a2.y + a3.y;
    float qxx = q0.x + q1.x + q2.x + q3.x;
    float qyy = q0.y + q1.y + q2.y + q3.y;
    float* sb = s12b + (size_t)(blockIdx.x & (SBANKS - 1)) * 256;
    atomicAdd(&sb[lane * 2], ax);
    atomicAdd(&sb[lane * 2 + 1], ay);
    atomicAdd(&sb[128 + lane * 2], qxx);
    atomicAdd(&sb[128 + lane * 2 + 1], qyy);
  }
}

// bnfin: sum 32 banks, compute scale/shift, re-zero banks
__global__ void k_bnfin(float* __restrict__ s12b, const float* __restrict__ gam,
                        const float* __restrict__ bet, float* __restrict__ scsh,
                        float invN) {
  int j = threadIdx.x;  // 0..127 (column)
  float sum = 0.f, sq = 0.f;
#pragma unroll
  for (int bk = 0; bk < SBANKS; ++bk) {
    sum += s12b[(size_t)bk * 256 + j];
    sq += s12b[(size_t)bk * 256 + 128 + j];
  }
  float mu = sum * invN;
  float var = sq * invN - mu * mu;
  float sc = gam[j] * rsqrtf(var + 1e-5f);
  scsh[j] = sc;
  scsh[128 + j] = bet[j] - mu * sc;
#pragma unroll
  for (int bk = 0; bk < SBANKS; ++bk) {
    s12b[(size_t)bk * 256 + j] = 0.f;
    s12b[(size_t)bk * 256 + 128 + j] = 0.f;
  }
}

// merged pooling: blocks [0,G) graph pool; [G,G+M) motif pool via CSR
__global__ __launch_bounds__(256) void k_poolgm(
    const float* __restrict__ y, const int* __restrict__ gid,
    const int* __restrict__ mrp, const int* __restrict__ mlist,
    const float* __restrict__ scsh, float* __restrict__ out,
    float* __restrict__ xcat, int N, int G) {
  int b = blockIdx.x, t = threadIdx.x;
  int col = t & 127, half = t >> 7;
  const float* scale = scsh;
  const float* shift = scsh + 128;
  float acc = 0.f;
  int beg, end;
  if (b < G) {
    int g = b;
    int lo = 0, hi = N;
    while (lo < hi) { int m = (lo + hi) >> 1; if (gid[m] < g) lo = m + 1; else hi = m; }
    beg = lo;
    hi = N;
    while (lo < hi) { int m = (lo + hi) >> 1; if (gid[m] <= g) lo = m + 1; else hi = m; }
    end = lo;
    for (int r = beg + half; r < end; r += 2) acc += y[(size_t)r * D128 + col];
  } else {
    int m = b - G + 1;
    beg = mrp[m]; end = mrp[m + 1];
    for (int r = beg + half; r < end; r += 2) {
      int n = mlist[r];
      acc += y[(size_t)n * D128 + col];
    }
  }
  __shared__ float ls[256];
  ls[t] = acc;
  __syncthreads();
  if (t < 128) {
    float v = ls[t] + ls[t + 128];
    v = v / fmaxf((float)(end - beg), 1.f);
    v = v * scale[t] + shift[t];
    xcat[(size_t)b * D128 + t] = v;
    if (b < G) out[(size_t)b * D128 + t] = v;
  }
}

// tiled GEMM: out = act(X[M,K] @ W[K,N] + b), BM=64 BN=64 BK=32
__global__ __launch_bounds__(256) void k_gemm64(
    const float* __restrict__ X, const float* __restrict__ W,
    const float* __restrict__ b, float* __restrict__ out,
    int Mrows, int K, int Ncols, int relu) {
  __shared__ float xs[64][33];
  __shared__ float ws[32][68];
  int t = threadIdx.x;
  int row0 = blockIdx.x * 64, col0 = blockIdx.y * 64;
  int tx = t & 15, ty = t >> 4;
  int j0 = tx * 4, r0 = ty * 4;
  float acc[4][4] = {};
  for (int k0 = 0; k0 < K; k0 += 32) {
    for (int i = t; i < 512; i += 256) {
      int r = i >> 3, c4 = i & 7;
      int gr = row0 + r;
      float4 v = make_float4(0.f, 0.f, 0.f, 0.f);
      if (gr < Mrows) v = *(const float4*)(X + (size_t)gr * K + k0 + c4 * 4);
      xs[r][c4 * 4 + 0] = v.x; xs[r][c4 * 4 + 1] = v.y;
      xs[r][c4 * 4 + 2] = v.z; xs[r][c4 * 4 + 3] = v.w;
    }
    for (int i = t; i < 512; i += 256) {
      int r = i >> 4, c4 = i & 15;
      float4 v = *(const float4*)(W + (size_t)(k0 + r) * Ncols + col0 + c4 * 4);
      *(float4*)(&ws[r][c4 * 4]) = v;
    }
    __syncthreads();
#pragma unroll
    for (int kk = 0; kk < 32; ++kk) {
      float a_[4];
#pragma unroll
      for (int r = 0; r < 4; ++r) a_[r] = xs[r0 + r][kk];
      float4 wv = *(const float4*)(&ws[kk][j0]);
      float b_[4] = {wv.x, wv.y, wv.z, wv.w};
#pragma unroll
      for (int r = 0; r < 4; ++r)
#pragma unroll
        for (int j = 0; j < 4; ++j) acc[r][j] += a_[r] * b_[j];
    }
    __syncthreads();
  }
  float4 bb = *(const float4*)(b + col0 + j0);
  float ba[4] = {bb.x, bb.y, bb.z, bb.w};
#pragma unroll
  for (int r = 0; r < 4; ++r) {
    int gr = row0 + r0 + r;
    if (gr >= Mrows) continue;
    float4 o;
    o.x = acc[r][0] + ba[0]; o.y = acc[r][1] + ba[1];
    o.z = acc[r][2] + ba[2]; o.w = acc[r][3] + ba[3];
    if (relu) {
      o.x = fmaxf(o.x, 0.f); o.y = fmaxf(o.y, 0.f);
      o.z = fmaxf(o.z, 0.f); o.w = fmaxf(o.w, 0.f);
    }
    *(float4*)(out + (size_t)gr * Ncols + col0 + j0) = o;
  }
}

extern "C" void kernel_launch(void* const* d_in, const int* in_sizes, int n_in,
                              void* d_out, int out_size, void* d_ws, size_t ws_size,
                              hipStream_t stream) {
  (void)n_in; (void)out_size; (void)ws_size;
  const float* nf   = (const float*)d_in[0];
  const int*   src  = (const int*)d_in[1];
  const int*   dst  = (const int*)d_in[2];
  const int*   gid  = (const int*)d_in[3];
  const int*   mid  = (const int*)d_in[4];
  const float* Wg   = (const float*)d_in[5];
  const float* bg   = (const float*)d_in[6];
  const float* Wr   = (const float*)d_in[7];
  const float* br   = (const float*)d_in[8];
  const float* gam  = (const float*)d_in[9];
  const float* bet  = (const float*)d_in[10];
  const float* Wf   = (const float*)d_in[11];
  const float* bf   = (const float*)d_in[12];
  const float* W1   = (const float*)d_in[13];
  const float* b1   = (const float*)d_in[14];
  const float* W2   = (const float*)d_in[15];
  const float* b2   = (const float*)d_in[16];

  const int N = in_sizes[0] / D128;
  const int E = in_sizes[1];
  const int G = 512;
  const int M = 2048;
  const int R = G + M;

  char* ws = (char*)d_ws;
  size_t off = 0;
  auto alloc = [&](size_t bytes) -> void* {
    void* p = ws + off;
    off = (off + bytes + 255) & ~(size_t)255;
    return p;
  };
  unsigned short* hwb  = (unsigned short*)alloc((size_t)N * D128 * 2);
  unsigned short* resb = (unsigned short*)alloc((size_t)N * D128 * 2);
  float* yres = (float*)alloc((size_t)N * D128 * 4);
  // zero block: dego | degi | cntm | s12b[32*256]
  int*   zblk = (int*)alloc((size_t)(2 * N + (M + 1) + SBANKS * 256) * 4);
  int*   dego = zblk;
  int*   degi = zblk + N;
  int*   cntm = zblk + 2 * N;
  float* s12b = (float*)(zblk + 2 * N + (M + 1));
  float* ns   = (float*)alloc((size_t)N * 4);
  float* nd   = (float*)alloc((size_t)N * 4);
  int*   rp   = (int*)alloc((size_t)(N + 1) * 4);
  int*   mrp  = (int*)alloc((size_t)(M + 2) * 4);
  int*   csrc = (int*)alloc((size_t)E * 4);
  int*   mlist= (int*)alloc((size_t)N * 4);
  int*   pe   = (int*)alloc((size_t)E * 4);
  int*   pn   = (int*)alloc((size_t)N * 4);
  int*   psum = (int*)alloc(128 * 4);
  float* scsh = (float*)alloc(256 * 4);
  unsigned short* wp = (unsigned short*)alloc((size_t)3 * 2 * 2 * 16384 * 2);
  float* xcat = (float*)alloc((size_t)R * D128 * 4);
  float* fbuf = (float*)alloc((size_t)R * 256 * 4);
  float* zbuf = (float*)alloc((size_t)R * 256 * 4);

  float* outg  = (float*)d_out;             // graph_feats [512,128]
  float* outgl = outg + (size_t)G * D128;   // out_global then out_sub

  const int EB = (E + 255) / 256;
  const int NB = (N + 255) / 256;
  const int nb1 = (N + 1023) / 1024;
  const int nb2 = (M + 1 + 1023) / 1024;
  const int AGRID = 1024;

  hipMemsetAsync(zblk, 0, (size_t)(2 * N + (M + 1) + SBANKS * 256) * 4, stream);

  k_prep0<<<EB + NB + 48, 256, 0, stream>>>(src, dst, mid, Wg, Wr, dego, degi,
                                            cntm, pe, pn, wp, E, N, EB, NB);
  k_part2<<<NB + nb1 + nb2, 256, 0, stream>>>(dego, degi, cntm, ns, nd, scsh,
                                              psum, N, M + 1, NB, nb1);
  k_scanp2<<<1, 128, 0, stream>>>(psum, nb1, nb2);
  k_scat2<<<nb1 + nb2, 256, 0, stream>>>(degi, cntm, psum, rp, mrp, N, M + 1, nb1, nb2);
  k_csrm<<<EB + NB, 256, 0, stream>>>(src, dst, pe, mid, pn, rp, mrp,
                                      csrc, mlist, E, N, EB);

  const float* hin = nf;
  for (int l = 0; l < 3; ++l) {
    k_dualmfma<<<(N + 63) / 64, 256, 0, stream>>>(hin, wp + (size_t)l * 65536,
                                                  br + l * D128, ns, scsh, hwb, resb, N);
    k_agg<<<AGRID, 256, 0, stream>>>(hwb, resb, rp, csrc, nd, bg + l * D128,
                                     yres, s12b, N);
    k_bnfin<<<1, 128, 0, stream>>>(s12b, gam + l * D128, bet + l * D128,
                                   scsh, 1.f / (float)N);
    hin = yres;
  }

  k_poolgm<<<G + M, 256, 0, stream>>>(yres, gid, mrp, mlist, scsh, outg, xcat, N, G);

  dim3 g1((R + 63) / 64, 256 / 64);
  k_gemm64<<<g1, 256, 0, stream>>>(xcat, Wf, bf, fbuf, R, 128, 256, 0);
  dim3 g2((R + 63) / 64, 256 / 64);
  k_gemm64<<<g2, 256, 0, stream>>>(fbuf, W1, b1, zbuf, R, 256, 256, 1);
  dim3 g3((R + 63) / 64, 128 / 64);
  k_gemm64<<<g3, 256, 0, stream>>>(zbuf, W2, b2, outgl, R, 256, 128, 0);
}

// Round 14
// 426.472 us; speedup vs baseline: 1.7705x; 1.0307x over previous
//
#include <hip/hip_runtime.h>

// ---------------------------------------------------------------------------
// GCN forward: 3x (split-bf16 MFMA dual GEMM -> fused gather-agg+BN-stats)
// -> CSR pooled readouts -> batched MLP head.
// Round 13: degree histograms moved OFF the fabric: LDS-privatized dual
// histogram (13 node-ranges x 32 edge-chunks), LDS-atomic return = local
// ordinal (pe_loc); k_hred reduces partials -> dego/degi and prefix-sums
// chunk offsets in place. Replaces ~1.2M fabric atomics (71us) w/ streaming.
// ---------------------------------------------------------------------------

#define D128 128
#define SBANKS 32
#define NRR 4096      // nodes per range (power of 2)
#define CCH 32        // edge chunks

typedef short bf16x8 __attribute__((ext_vector_type(8)));
typedef unsigned short u16x8 __attribute__((ext_vector_type(8)));
typedef float f32x4 __attribute__((ext_vector_type(4)));

static __device__ __forceinline__ unsigned short f2bf(float x) {
  unsigned u = __float_as_uint(x);
  unsigned r = (u + 0x7FFF + ((u >> 16) & 1)) >> 16;  // RNE
  return (unsigned short)r;
}
static __device__ __forceinline__ float bf2f(unsigned short b) {
  return __uint_as_float(((unsigned)b) << 16);
}

// hist2: [0,R*C): LDS dual histogram (dego by src, degi by dst) + pe_loc;
// [R*C, +NB): motif hist (global atomics, stores pn); [.., +48): wprep
__global__ __launch_bounds__(256) void k_hist2(
    const int* __restrict__ src, const int* __restrict__ dst,
    const int* __restrict__ mid, const float* __restrict__ Wg,
    const float* __restrict__ Wr, int* __restrict__ po,
    int* __restrict__ pi, int* __restrict__ pe_loc,
    int* __restrict__ cntm, int* __restrict__ pn,
    unsigned short* __restrict__ wp, int E, int N, int R, int chunkE, int NB) {
  __shared__ int lo_[NRR], li_[NRR];
  int b = blockIdx.x, t = threadIdx.x;
  int RC = R * CCH;
  if (b < RC) {
    int r = b / CCH, c = b - r * CCH;
    int base = r * NRR;
    for (int i = t; i < NRR; i += 256) { lo_[i] = 0; li_[i] = 0; }
    __syncthreads();
    int e0 = c * chunkE;
    int e1 = min(e0 + chunkE, E);
    for (int e = e0 + t; e < e1; e += 256) {
      int s = src[e], d = dst[e];
      unsigned so = (unsigned)(s - base), dofs = (unsigned)(d - base);
      if (so < NRR) atomicAdd(&lo_[so], 1);
      if (dofs < NRR) pe_loc[e] = atomicAdd(&li_[dofs], 1);
    }
    __syncthreads();
    int* pos = po + (size_t)b * NRR;
    int* pis = pi + (size_t)b * NRR;
    for (int i = t; i < NRR; i += 256) {
      pos[i] = lo_[i];
      pis[i] = li_[i];
    }
    return;
  }
  b -= RC;
  if (b < NB) {
    int i = b * 256 + t;
    if (i < N) pn[i] = atomicAdd(&cntm[mid[i]], 1);
    return;
  }
  b -= NB;
  int idx = b * 256 + t;  // < 12288
  int lane = idx & 63;
  int fs = (idx >> 6) & 31;
  int m = (idx >> 11) & 1;
  int l = idx >> 12;
  int cb = fs >> 2, s = fs & 3;
  const float* W = (m == 0 ? Wg : Wr) + (size_t)l * 16384;
  int n = cb * 16 + (lane & 15);
  int k0 = s * 32 + (lane >> 4) * 8;
  unsigned short* hi = wp + ((size_t)(l * 2 + m)) * 32768 + ((size_t)fs * 64 + lane) * 8;
  unsigned short* lo = hi + 16384;
#pragma unroll
  for (int j = 0; j < 8; ++j) {
    float x = W[(size_t)(k0 + j) * D128 + n];
    unsigned short h = f2bf(x);
    hi[j] = h;
    lo[j] = f2bf(x - bf2f(h));
  }
}

// hred: per node, sum po over chunks -> dego; exclusive-prefix pi over chunks
// (in place, giving chunk offsets) -> degi = total
__global__ __launch_bounds__(256) void k_hred(
    int* __restrict__ po, int* __restrict__ pi,
    int* __restrict__ dego, int* __restrict__ degi, int N, int R) {
  int n = blockIdx.x * 256 + threadIdx.x;
  if (n >= R * NRR) return;
  int r = n >> 12, off = n & (NRR - 1);
  size_t base = ((size_t)r * CCH) * NRR + off;
  int so = 0, run = 0;
#pragma unroll 4
  for (int c = 0; c < CCH; ++c) {
    size_t idx = base + (size_t)c * NRR;
    so += po[idx];
    int v = pi[idx];
    pi[idx] = run;
    run += v;
  }
  if (n < N) {
    dego[n] = so;
    degi[n] = run;
  }
}

// part2 (+norm): blocks [0,NB): norm + scsh init; [NB,NB+nb1): partials over
// degi; [NB+nb1,..): partials over cntm
__global__ __launch_bounds__(256) void k_part2(
    const int* __restrict__ dego, const int* __restrict__ degi,
    const int* __restrict__ cntm, float* __restrict__ ns,
    float* __restrict__ nd, float* __restrict__ scsh,
    int* __restrict__ psum, int N, int M1, int NB, int nb1) {
  int b = blockIdx.x, t = threadIdx.x;
  if (b < NB) {
    int i = b * 256 + t;
    if (i < N) {
      ns[i] = rsqrtf(fmaxf((float)dego[i], 1.f));
      nd[i] = rsqrtf(fmaxf((float)degi[i], 1.f));
    }
    if (b == 0 && t < 128) {
      scsh[t] = 1.f;
      scsh[128 + t] = 0.f;
    }
    return;
  }
  b -= NB;
  const int* a = degi;
  int n = N, bb = b, out = b;
  if (b >= nb1) { a = cntm; n = M1; bb = b - nb1; out = 64 + bb; }
  int i = bb * 1024 + t * 4;
  int4 v = make_int4(0, 0, 0, 0);
  if (i + 3 < n) v = *(const int4*)(a + i);
  else {
    if (i < n) v.x = a[i];
    if (i + 1 < n) v.y = a[i + 1];
    if (i + 2 < n) v.z = a[i + 2];
    if (i + 3 < n) v.w = a[i + 3];
  }
  int s = v.x + v.y + v.z + v.w;
#pragma unroll
  for (int off = 1; off < 64; off <<= 1) s += __shfl_xor(s, off);
  __shared__ int wsum[4];
  if ((t & 63) == 0) wsum[t >> 6] = s;
  __syncthreads();
  if (t == 0) psum[out] = wsum[0] + wsum[1] + wsum[2] + wsum[3];
}

// single block: two wave-level exclusive scans (nb1<=64, nb2<=64)
__global__ __launch_bounds__(128) void k_scanp2(int* __restrict__ psum, int nb1, int nb2) {
  int t = threadIdx.x;
  int lane = t & 63;
  int* p = (t < 64) ? psum : psum + 64;
  int nb = (t < 64) ? nb1 : nb2;
  int x = (lane < nb) ? p[lane] : 0;
  int s = x;
#pragma unroll
  for (int off = 1; off < 64; off <<= 1) {
    int u = __shfl_up(s, off);
    if (lane >= off) s += u;
  }
  if (lane < nb) p[lane] = s - x;
}

// merged scatter-scan
__global__ __launch_bounds__(256) void k_scat2(const int* __restrict__ a1,
                                               const int* __restrict__ a2,
                                               const int* __restrict__ psum,
                                               int* __restrict__ rp1,
                                               int* __restrict__ rp2,
                                               int n1, int n2, int nb1, int nb2) {
  int b = blockIdx.x, t = threadIdx.x;
  const int* a = a1;
  const int* ps = psum;
  int* rp = rp1;
  int n = n1, bb = b, nb = nb1;
  if (b >= nb1) { a = a2; ps = psum + 64; rp = rp2; n = n2; bb = b - nb1; nb = nb2; }
  int i = bb * 1024 + t * 4;
  int4 v = make_int4(0, 0, 0, 0);
  if (i + 3 < n) v = *(const int4*)(a + i);
  else {
    if (i < n) v.x = a[i];
    if (i + 1 < n) v.y = a[i + 1];
    if (i + 2 < n) v.z = a[i + 2];
    if (i + 3 < n) v.w = a[i + 3];
  }
  int s = v.x + v.y + v.z + v.w;
  __shared__ int buf[256];
  buf[t] = s;
  __syncthreads();
  for (int off = 1; off < 256; off <<= 1) {
    int u = (t >= off) ? buf[t - off] : 0;
    __syncthreads();
    buf[t] += u;
    __syncthreads();
  }
  int ex = buf[t] - s + ps[bb];
  int4 o;
  o.x = ex; o.y = ex + v.x; o.z = ex + v.x + v.y; o.w = ex + v.x + v.y + v.z;
  if (i + 3 < n) *(int4*)(rp + i) = o;
  else {
    if (i < n) rp[i] = o.x;
    if (i + 1 < n) rp[i + 1] = o.y;
    if (i + 2 < n) rp[i + 2] = o.z;
    if (i + 3 < n) rp[i + 3] = o.w;
  }
  if (bb == nb - 1 && t == 255) rp[n] = ex + s;
}

// ATOMIC-FREE CSR scatter: pe_full = chunk_offset(pi) + pe_loc
// [0,EB) edges -> csrc ; [EB,EB+NB) nodes -> mlist
__global__ __launch_bounds__(256) void k_csrm(
    const int* __restrict__ src, const int* __restrict__ dst,
    const int* __restrict__ pe_loc, const int* __restrict__ pi,
    const int* __restrict__ mid, const int* __restrict__ pn,
    const int* __restrict__ rp, const int* __restrict__ mrp,
    int* __restrict__ csrc, int* __restrict__ mlist,
    int E, int N, int EB, int chunkE) {
  int b = blockIdx.x, t = threadIdx.x;
  if (b < EB) {
    int e = b * 256 + t;
    if (e < E) {
      int d = dst[e];
      int c = e / chunkE;
      int r = d >> 12, off = d & (NRR - 1);
      int coff = pi[(((size_t)r * CCH) + c) * NRR + off];
      csrc[rp[d] + coff + pe_loc[e]] = src[e];
    }
    return;
  }
  int n = (b - EB) * 256 + t;
  if (n < N) {
    int m = mid[n];
    mlist[mrp[m] + pn[n]] = n;
  }
}

// split-bf16 MFMA dual GEMM: 64 rows x 256 cols (Wg|Wr) per block, 4 waves.
// hwb (bf16) = (hn @ Wg) * ns ; resb (bf16) = relu(hn @ Wr + br)
__global__ __launch_bounds__(256) void k_dualmfma(
    const float* __restrict__ h, const unsigned short* __restrict__ wpl,
    const float* __restrict__ brl, const float* __restrict__ ns,
    const float* __restrict__ scsh, unsigned short* __restrict__ hwb,
    unsigned short* __restrict__ resb, int N) {
  __shared__ __align__(16) unsigned char smem[32768];  // hi[64][256B] | lo
  int t = threadIdx.x;
  int row0 = blockIdx.x * 64;
  const float* scale = scsh;
  const float* shift = scsh + 128;

#pragma unroll
  for (int q = 0; q < 4; ++q) {
    int chunk = q * 256 + t;
    int r = chunk >> 4;
    int c8 = chunk & 15;
    int gr = row0 + r;
    float xs[8];
    if (gr < N) {
      const float4* hp = (const float4*)(h + (size_t)gr * D128 + c8 * 8);
      float4 v0 = hp[0], v1 = hp[1];
      float4 sc0 = ((const float4*)scale)[c8 * 2];
      float4 sc1 = ((const float4*)scale)[c8 * 2 + 1];
      float4 sh0 = ((const float4*)shift)[c8 * 2];
      float4 sh1 = ((const float4*)shift)[c8 * 2 + 1];
      xs[0] = v0.x * sc0.x + sh0.x; xs[1] = v0.y * sc0.y + sh0.y;
      xs[2] = v0.z * sc0.z + sh0.z; xs[3] = v0.w * sc0.w + sh0.w;
      xs[4] = v1.x * sc1.x + sh1.x; xs[5] = v1.y * sc1.y + sh1.y;
      xs[6] = v1.z * sc1.z + sh1.z; xs[7] = v1.w * sc1.w + sh1.w;
    } else {
#pragma unroll
      for (int j = 0; j < 8; ++j) xs[j] = 0.f;
    }
    u16x8 hi8, lo8;
#pragma unroll
    for (int j = 0; j < 8; ++j) {
      unsigned short hb = f2bf(xs[j]);
      hi8[j] = hb;
      lo8[j] = f2bf(xs[j] - bf2f(hb));
    }
    int sw = (c8 * 16) ^ ((r & 7) << 4);
    *(u16x8*)(&smem[r * 256 + sw]) = hi8;
    *(u16x8*)(&smem[16384 + r * 256 + sw]) = lo8;
  }
  __syncthreads();

  int w = t >> 6, l6 = t & 63;
  int mat = w >> 1, half = w & 1;
  const unsigned short* wpm = wpl + (size_t)mat * 32768;

  f32x4 acc[4][4];
#pragma unroll
  for (int rb = 0; rb < 4; ++rb)
#pragma unroll
    for (int cb = 0; cb < 4; ++cb) acc[rb][cb] = (f32x4){0.f, 0.f, 0.f, 0.f};

#pragma unroll
  for (int s = 0; s < 4; ++s) {
    bf16x8 ah[4], al[4];
    int kb = s * 64 + (l6 >> 4) * 16;
#pragma unroll
    for (int rb = 0; rb < 4; ++rb) {
      int row = rb * 16 + (l6 & 15);
      int off = row * 256 + (kb ^ ((row & 7) << 4));
      ah[rb] = *(const bf16x8*)(&smem[off]);
      al[rb] = *(const bf16x8*)(&smem[16384 + off]);
    }
    bf16x8 bh[4], bl[4];
#pragma unroll
    for (int cb = 0; cb < 4; ++cb) {
      const unsigned short* p = wpm + (((size_t)(half * 4 + cb) * 4 + s) * 64 + l6) * 8;
      bh[cb] = *(const bf16x8*)p;
      bl[cb] = *(const bf16x8*)(p + 16384);
    }
#pragma unroll
    for (int rb = 0; rb < 4; ++rb)
#pragma unroll
      for (int cb = 0; cb < 4; ++cb) {
        acc[rb][cb] = __builtin_amdgcn_mfma_f32_16x16x32_bf16(ah[rb], bh[cb], acc[rb][cb], 0, 0, 0);
        acc[rb][cb] = __builtin_amdgcn_mfma_f32_16x16x32_bf16(al[rb], bh[cb], acc[rb][cb], 0, 0, 0);
        acc[rb][cb] = __builtin_amdgcn_mfma_f32_16x16x32_bf16(ah[rb], bl[cb], acc[rb][cb], 0, 0, 0);
      }
  }

  int rsub = (l6 >> 4) * 4;
  int colb = half * 64 + (l6 & 15);
  if (mat == 0) {
#pragma unroll
    for (int rb = 0; rb < 4; ++rb)
#pragma unroll
      for (int reg = 0; reg < 4; ++reg) {
        int gr = row0 + rb * 16 + rsub + reg;
        if (gr >= N) continue;
        float sv = ns[gr];
        unsigned short* op = hwb + ((size_t)gr << 7) + colb;
#pragma unroll
        for (int cb = 0; cb < 4; ++cb) op[cb * 16] = f2bf(acc[rb][cb][reg] * sv);
      }
  } else {
    float bv[4];
#pragma unroll
    for (int cb = 0; cb < 4; ++cb) bv[cb] = brl[colb + cb * 16];
#pragma unroll
    for (int rb = 0; rb < 4; ++rb)
#pragma unroll
      for (int reg = 0; reg < 4; ++reg) {
        int gr = row0 + rb * 16 + rsub + reg;
        if (gr >= N) continue;
        unsigned short* op = resb + ((size_t)gr << 7) + colb;
#pragma unroll
        for (int cb = 0; cb < 4; ++cb)
          op[cb * 16] = f2bf(fmaxf(acc[rb][cb][reg] + bv[cb], 0.f));
      }
  }
}

// grid-stride agg + fused BN stats: y = relu(agg*nd+bg)+res(bf16) -> yres f32;
// per-thread (sum,sumsq), LDS cross-wave reduce, banked atomics.
__global__ __launch_bounds__(256) void k_agg(
    const unsigned short* __restrict__ hwb, const unsigned short* __restrict__ resb,
    const int* __restrict__ rp, const int* __restrict__ csrc,
    const float* __restrict__ nd, const float* __restrict__ bgl,
    float* __restrict__ yres, float* __restrict__ s12b, int N) {
  int w = threadIdx.x >> 6, lane = threadIdx.x & 63;
  float2 b = ((const float2*)bgl)[lane];
  float sx = 0.f, sy = 0.f, qx = 0.f, qy = 0.f;
  for (int n = blockIdx.x * 4 + w; n < N; n += gridDim.x * 4) {
    int beg = rp[n], end = rp[n + 1];
    float ax = 0.f, ay = 0.f;
    for (int e0 = beg; e0 < end; e0 += 64) {
      int cnt = min(end - e0, 64);
      int sreg = (lane < cnt) ? csrc[e0 + lane] : 0;
      int j = 0;
      for (; j + 8 <= cnt; j += 8) {
        unsigned v[8];
#pragma unroll
        for (int u = 0; u < 8; ++u) {
          int s = __shfl(sreg, j + u);
          v[u] = *(const unsigned*)(hwb + (((size_t)s) << 7) + lane * 2);
        }
#pragma unroll
        for (int u = 0; u < 8; ++u) {
          ax += bf2f((unsigned short)(v[u] & 0xffffu));
          ay += bf2f((unsigned short)(v[u] >> 16));
        }
      }
      for (; j + 4 <= cnt; j += 4) {
        unsigned v[4];
#pragma unroll
        for (int u = 0; u < 4; ++u) {
          int s = __shfl(sreg, j + u);
          v[u] = *(const unsigned*)(hwb + (((size_t)s) << 7) + lane * 2);
        }
#pragma unroll
        for (int u = 0; u < 4; ++u) {
          ax += bf2f((unsigned short)(v[u] & 0xffffu));
          ay += bf2f((unsigned short)(v[u] >> 16));
        }
      }
      for (; j < cnt; ++j) {
        int s = __shfl(sreg, j);
        unsigned v = *(const unsigned*)(hwb + (((size_t)s) << 7) + lane * 2);
        ax += bf2f((unsigned short)(v & 0xffffu));
        ay += bf2f((unsigned short)(v >> 16));
      }
    }
    float ndv = nd[n];
    unsigned rv = *(const unsigned*)(resb + (((size_t)n) << 7) + lane * 2);
    float2 y;
    y.x = fmaxf(ax * ndv + b.x, 0.f) + bf2f((unsigned short)(rv & 0xffffu));
    y.y = fmaxf(ay * ndv + b.y, 0.f) + bf2f((unsigned short)(rv >> 16));
    ((float2*)yres)[(size_t)n * 64 + lane] = y;
    sx += y.x; sy += y.y;
    qx += y.x * y.x; qy += y.y * y.y;
  }
  __shared__ float2 ssum[4][64], ssq[4][64];
  ssum[w][lane] = make_float2(sx, sy);
  ssq[w][lane] = make_float2(qx, qy);
  __syncthreads();
  if (w == 0) {
    float2 a0 = ssum[0][lane], a1 = ssum[1][lane], a2 = ssum[2][lane], a3 = ssum[3][lane];
    float2 q0 = ssq[0][lane], q1 = ssq[1][lane], q2 = ssq[2][lane], q3 = ssq[3][lane];
    float ax = a0.x + a1.x + a2.x + a3.x;
    float ay = a0.y + a1.y + a2.y + a3.y;
    float qxx = q0.x + q1.x + q2.x + q3.x;
    float qyy = q0.y + q1.y + q2.y + q3.y;
    float* sb = s12b + (size_t)(blockIdx.x & (SBANKS - 1)) * 256;
    atomicAdd(&sb[lane * 2], ax);
    atomicAdd(&sb[lane * 2 + 1], ay);
    atomicAdd(&sb[128 + lane * 2], qxx);
    atomicAdd(&sb[128 + lane * 2 + 1], qyy);
  }
}

// bnfin: sum 32 banks, compute scale/shift, re-zero banks
__global__ void k_bnfin(float* __restrict__ s12b, const float* __restrict__ gam,
                        const float* __restrict__ bet, float* __restrict__ scsh,
                        float invN) {
  int j = threadIdx.x;  // 0..127 (column)
  float sum = 0.f, sq = 0.f;
#pragma unroll
  for (int bk = 0; bk < SBANKS; ++bk) {
    sum += s12b[(size_t)bk * 256 + j];
    sq += s12b[(size_t)bk * 256 + 128 + j];
  }
  float mu = sum * invN;
  float var = sq * invN - mu * mu;
  float sc = gam[j] * rsqrtf(var + 1e-5f);
  scsh[j] = sc;
  scsh[128 + j] = bet[j] - mu * sc;
#pragma unroll
  for (int bk = 0; bk < SBANKS; ++bk) {
    s12b[(size_t)bk * 256 + j] = 0.f;
    s12b[(size_t)bk * 256 + 128 + j] = 0.f;
  }
}

// merged pooling: blocks [0,G) graph pool; [G,G+M) motif pool via CSR
__global__ __launch_bounds__(256) void k_poolgm(
    const float* __restrict__ y, const int* __restrict__ gid,
    const int* __restrict__ mrp, const int* __restrict__ mlist,
    const float* __restrict__ scsh, float* __restrict__ out,
    float* __restrict__ xcat, int N, int G) {
  int b = blockIdx.x, t = threadIdx.x;
  int col = t & 127, half = t >> 7;
  const float* scale = scsh;
  const float* shift = scsh + 128;
  float acc = 0.f;
  int beg, end;
  if (b < G) {
    int g = b;
    int lo = 0, hi = N;
    while (lo < hi) { int m = (lo + hi) >> 1; if (gid[m] < g) lo = m + 1; else hi = m; }
    beg = lo;
    hi = N;
    while (lo < hi) { int m = (lo + hi) >> 1; if (gid[m] <= g) lo = m + 1; else hi = m; }
    end = lo;
    for (int r = beg + half; r < end; r += 2) acc += y[(size_t)r * D128 + col];
  } else {
    int m = b - G + 1;
    beg = mrp[m]; end = mrp[m + 1];
    for (int r = beg + half; r < end; r += 2) {
      int n = mlist[r];
      acc += y[(size_t)n * D128 + col];
    }
  }
  __shared__ float ls[256];
  ls[t] = acc;
  __syncthreads();
  if (t < 128) {
    float v = ls[t] + ls[t + 128];
    v = v / fmaxf((float)(end - beg), 1.f);
    v = v * scale[t] + shift[t];
    xcat[(size_t)b * D128 + t] = v;
    if (b < G) out[(size_t)b * D128 + t] = v;
  }
}

// tiled GEMM: out = act(X[M,K] @ W[K,N] + b), BM=64 BN=64 BK=32
__global__ __launch_bounds__(256) void k_gemm64(
    const float* __restrict__ X, const float* __restrict__ W,
    const float* __restrict__ b, float* __restrict__ out,
    int Mrows, int K, int Ncols, int relu) {
  __shared__ float xs[64][33];
  __shared__ float ws[32][68];
  int t = threadIdx.x;
  int row0 = blockIdx.x * 64, col0 = blockIdx.y * 64;
  int tx = t & 15, ty = t >> 4;
  int j0 = tx * 4, r0 = ty * 4;
  float acc[4][4] = {};
  for (int k0 = 0; k0 < K; k0 += 32) {
    for (int i = t; i < 512; i += 256) {
      int r = i >> 3, c4 = i & 7;
      int gr = row0 + r;
      float4 v = make_float4(0.f, 0.f, 0.f, 0.f);
      if (gr < Mrows) v = *(const float4*)(X + (size_t)gr * K + k0 + c4 * 4);
      xs[r][c4 * 4 + 0] = v.x; xs[r][c4 * 4 + 1] = v.y;
      xs[r][c4 * 4 + 2] = v.z; xs[r][c4 * 4 + 3] = v.w;
    }
    for (int i = t; i < 512; i += 256) {
      int r = i >> 4, c4 = i & 15;
      float4 v = *(const float4*)(W + (size_t)(k0 + r) * Ncols + col0 + c4 * 4);
      *(float4*)(&ws[r][c4 * 4]) = v;
    }
    __syncthreads();
#pragma unroll
    for (int kk = 0; kk < 32; ++kk) {
      float a_[4];
#pragma unroll
      for (int r = 0; r < 4; ++r) a_[r] = xs[r0 + r][kk];
      float4 wv = *(const float4*)(&ws[kk][j0]);
      float b_[4] = {wv.x, wv.y, wv.z, wv.w};
#pragma unroll
      for (int r = 0; r < 4; ++r)
#pragma unroll
        for (int j = 0; j < 4; ++j) acc[r][j] += a_[r] * b_[j];
    }
    __syncthreads();
  }
  float4 bb = *(const float4*)(b + col0 + j0);
  float ba[4] = {bb.x, bb.y, bb.z, bb.w};
#pragma unroll
  for (int r = 0; r < 4; ++r) {
    int gr = row0 + r0 + r;
    if (gr >= Mrows) continue;
    float4 o;
    o.x = acc[r][0] + ba[0]; o.y = acc[r][1] + ba[1];
    o.z = acc[r][2] + ba[2]; o.w = acc[r][3] + ba[3];
    if (relu) {
      o.x = fmaxf(o.x, 0.f); o.y = fmaxf(o.y, 0.f);
      o.z = fmaxf(o.z, 0.f); o.w = fmaxf(o.w, 0.f);
    }
    *(float4*)(out + (size_t)gr * Ncols + col0 + j0) = o;
  }
}

extern "C" void kernel_launch(void* const* d_in, const int* in_sizes, int n_in,
                              void* d_out, int out_size, void* d_ws, size_t ws_size,
                              hipStream_t stream) {
  (void)n_in; (void)out_size; (void)ws_size;
  const float* nf   = (const float*)d_in[0];
  const int*   src  = (const int*)d_in[1];
  const int*   dst  = (const int*)d_in[2];
  const int*   gid  = (const int*)d_in[3];
  const int*   mid  = (const int*)d_in[4];
  const float* Wg   = (const float*)d_in[5];
  const float* bg   = (const float*)d_in[6];
  const float* Wr   = (const float*)d_in[7];
  const float* br   = (const float*)d_in[8];
  const float* gam  = (const float*)d_in[9];
  const float* bet  = (const float*)d_in[10];
  const float* Wf   = (const float*)d_in[11];
  const float* bf   = (const float*)d_in[12];
  const float* W1   = (const float*)d_in[13];
  const float* b1   = (const float*)d_in[14];
  const float* W2   = (const float*)d_in[15];
  const float* b2   = (const float*)d_in[16];

  const int N = in_sizes[0] / D128;
  const int E = in_sizes[1];
  const int G = 512;
  const int M = 2048;
  const int R2 = G + M;
  const int R = (N + NRR - 1) / NRR;         // node ranges (13 for N=50000)
  const int chunkE = (E + CCH - 1) / CCH;

  char* ws = (char*)d_ws;
  size_t off = 0;
  auto alloc = [&](size_t bytes) -> void* {
    void* p = ws + off;
    off = (off + bytes + 255) & ~(size_t)255;
    return p;
  };
  unsigned short* hwb  = (unsigned short*)alloc((size_t)N * D128 * 2);
  unsigned short* resb = (unsigned short*)alloc((size_t)N * D128 * 2);
  float* yres = (float*)alloc((size_t)N * D128 * 4);
  // zero block: cntm | s12b[32*256]  (dego/degi now fully written by k_hred)
  int*   zblk = (int*)alloc((size_t)((M + 1) + SBANKS * 256) * 4);
  int*   cntm = zblk;
  float* s12b = (float*)(zblk + (M + 1));
  int*   dego = (int*)alloc((size_t)N * 4);
  int*   degi = (int*)alloc((size_t)N * 4);
  int*   po   = (int*)alloc((size_t)R * CCH * NRR * 4);
  int*   pi   = (int*)alloc((size_t)R * CCH * NRR * 4);
  float* ns   = (float*)alloc((size_t)N * 4);
  float* nd   = (float*)alloc((size_t)N * 4);
  int*   rp   = (int*)alloc((size_t)(N + 1) * 4);
  int*   mrp  = (int*)alloc((size_t)(M + 2) * 4);
  int*   csrc = (int*)alloc((size_t)E * 4);
  int*   mlist= (int*)alloc((size_t)N * 4);
  int*   pe   = (int*)alloc((size_t)E * 4);
  int*   pn   = (int*)alloc((size_t)N * 4);
  int*   psum = (int*)alloc(128 * 4);
  float* scsh = (float*)alloc(256 * 4);
  unsigned short* wp = (unsigned short*)alloc((size_t)3 * 2 * 2 * 16384 * 2);
  float* xcat = (float*)alloc((size_t)R2 * D128 * 4);
  float* fbuf = (float*)alloc((size_t)R2 * 256 * 4);
  float* zbuf = (float*)alloc((size_t)R2 * 256 * 4);

  float* outg  = (float*)d_out;             // graph_feats [512,128]
  float* outgl = outg + (size_t)G * D128;   // out_global then out_sub

  const int EB = (E + 255) / 256;
  const int NB = (N + 255) / 256;
  const int nb1 = (N + 1023) / 1024;
  const int nb2 = (M + 1 + 1023) / 1024;
  const int AGRID = 1024;

  hipMemsetAsync(zblk, 0, (size_t)((M + 1) + SBANKS * 256) * 4, stream);

  k_hist2<<<R * CCH + NB + 48, 256, 0, stream>>>(src, dst, mid, Wg, Wr, po, pi,
                                                 pe, cntm, pn, wp, E, N, R,
                                                 chunkE, NB);
  k_hred<<<(R * NRR) / 256, 256, 0, stream>>>(po, pi, dego, degi, N, R);
  k_part2<<<NB + nb1 + nb2, 256, 0, stream>>>(dego, degi, cntm, ns, nd, scsh,
                                              psum, N, M + 1, NB, nb1);
  k_scanp2<<<1, 128, 0, stream>>>(psum, nb1, nb2);
  k_scat2<<<nb1 + nb2, 256, 0, stream>>>(degi, cntm, psum, rp, mrp, N, M + 1, nb1, nb2);
  k_csrm<<<EB + NB, 256, 0, stream>>>(src, dst, pe, pi, mid, pn, rp, mrp,
                                      csrc, mlist, E, N, EB, chunkE);

  const float* hin = nf;
  for (int l = 0; l < 3; ++l) {
    k_dualmfma<<<(N + 63) / 64, 256, 0, stream>>>(hin, wp + (size_t)l * 65536,
                                                  br + l * D128, ns, scsh, hwb, resb, N);
    k_agg<<<AGRID, 256, 0, stream>>>(hwb, resb, rp, csrc, nd, bg + l * D128,
                                     yres, s12b, N);
    k_bnfin<<<1, 128, 0, stream>>>(s12b, gam + l * D128, bet + l * D128,
                                   scsh, 1.f / (float)N);
    hin = yres;
  }

  k_poolgm<<<G + M, 256, 0, stream>>>(yres, gid, mrp, mlist, scsh, outg, xcat, N, G);

  dim3 g1((R2 + 63) / 64, 256 / 64);
  k_gemm64<<<g1, 256, 0, stream>>>(xcat, Wf, bf, fbuf, R2, 128, 256, 0);
  dim3 g2((R2 + 63) / 64, 256 / 64);
  k_gemm64<<<g2, 256, 0, stream>>>(fbuf, W1, b1, zbuf, R2, 256, 256, 1);
  dim3 g3((R2 + 63) / 64, 128 / 64);
  k_gemm64<<<g3, 256, 0, stream>>>(zbuf, W2, b2, outgl, R2, 256, 128, 0);
}